// Round 1
// baseline (932.396 us; speedup 1.0000x reference)
//
#include <hip/hip_runtime.h>

typedef unsigned short u16;
typedef unsigned int u32;
typedef unsigned long long u64;
typedef __bf16 bf16x8 __attribute__((ext_vector_type(8)));
typedef float f32x4 __attribute__((ext_vector_type(4)));

#define MFMA16(a, b, c) __builtin_amdgcn_mfma_f32_16x16x32_bf16(a, b, c, 0, 0, 0)

static __device__ __forceinline__ u16 f2bf(float f) {
  union { float f; u32 u; } v; v.f = f;
  u32 u = v.u;
  u32 r = (u + 0x7FFFu + ((u >> 16) & 1u)) >> 16;  // RNE
  return (u16)r;
}

static __device__ __forceinline__ bf16x8 ld16(const u16* p) {
  return __builtin_bit_cast(bf16x8, *(const uint4*)p);
}

static __device__ __forceinline__ u64 u64min(u64 a, u64 b) { return a < b ? a : b; }

// In-wave bitonic sort of 64 u64 keys, ascending by lane.
static __device__ __forceinline__ u64 bitonic64(u64 v, int lane) {
#pragma unroll
  for (int k = 2; k <= 64; k <<= 1) {
#pragma unroll
    for (int j = k >> 1; j > 0; j >>= 1) {
      u64 o = __shfl_xor(v, j, 64);
      bool up = ((lane & k) == 0);
      bool lower = ((lane & j) == 0);
      u64 mn = v < o ? v : o;
      u64 mx = v < o ? o : v;
      v = (lower == up) ? mn : mx;
    }
  }
  return v;
}

// In-wave bitonic sort of 64 f32 (no NaN), ascending by lane.
static __device__ __forceinline__ float bitonic64f(float v, int lane) {
#pragma unroll
  for (int k = 2; k <= 64; k <<= 1) {
#pragma unroll
    for (int j = k >> 1; j > 0; j >>= 1) {
      float o = __shfl_xor(v, j, 64);
      bool up = ((lane & k) == 0);
      bool lower = ((lane & j) == 0);
      float mn = fminf(v, o);
      float mx = fmaxf(v, o);
      v = (lower == up) ? mn : mx;
    }
  }
  return v;
}

// monotone u32 key from f32 bits — pure integer transform (safe to duplicate)
static __device__ __forceinline__ u32 fkey(float f) {
  u32 bb = __float_as_uint(f);
  u32 sgn = (u32)((int)bb >> 31);
  return bb ^ (sgn | 0x80000000u);
}

// Reference fp32 distance semantics (matches np, verified r3..r16):
//   dot = fma(z,bz, fma(y,by, mul(x,bx)));  d2 = fl(fl(s1+s2) - fl(2*dot))
static __device__ __forceinline__ float d2of(float x, float y, float z, float s1,
                                             f32x4 c) {
  float dt = __builtin_fmaf(z, c[2], __builtin_fmaf(y, c[1], __fmul_rn(x, c[0])));
  return __fsub_rn(__fadd_rn(s1, c[3]), __fmul_rn(2.0f, dt));
}

// ---------------------------------------------------------------------------
// K1: PREP + KNN-16. Restructured for occupancy: 512-thread blocks (8 waves)
// share one 64 KB candL; 4 rows/wave (was 8) at grid 512 → total rows same.
// LDS/block ~69.6 KB → 2 blocks/CU × 8 waves = 16 waves/CU = 4 waves/SIMD
// (was 8 waves/CU): 2x the latency hiding for the bitonic shuffle chains.
// Inner distance/sort math is VERBATIM (exact fp32 reference semantics).
// Survivor compaction switched from serialized LDS atomicAdd to ballot+mbcnt
// prefix (order differs; bitonic sort of surv normalizes it) with a
// wave-uniform skip of empty candidate groups.
// ---------------------------------------------------------------------------
__global__ __launch_bounds__(512, 4) void knn_prep(
    const float* __restrict__ xyz1, const float* __restrict__ xyz2,
    const float* __restrict__ points1, const float* __restrict__ points2,
    const float* __restrict__ W1, const float* __restrict__ W2,
    u16* __restrict__ p1t, u16* __restrict__ p2t,
    u16* __restrict__ W1b, u16* __restrict__ W2b,
    int* __restrict__ knn) {
  __shared__ __align__(16) char LB[65536];
  f32x4* candL = (f32x4*)LB;     // 4096 * 16 B (knn phase)
  u16* tile = (u16*)LB;          // 64*66*2 = 8448 B (transpose phase)
  __shared__ u64 surv[8][64];    // 4 KB
  const int t = threadIdx.x;
  const int lane = t & 63;
  const int w = t >> 6;
  const int g = blockIdx.x;

  // ---- part 0: W cast (blocks 0..71, 512 threads each = 36864 items) -----
  if (g < 72) {
    int i = g * 512 + t;
    if (i < 128 * 160) {
      int r = i / 160, c = i - r * 160;
      W1b[i] = (c < 131) ? f2bf(W1[r * 131 + c]) : (u16)0;
    } else {
      int u = i - 128 * 160;
      W2b[u] = f2bf(W2[u]);
    }
  }

  // ---- part 1: one transpose tile per block (512 threads) ----------------
  {
    const float* src = (g < 256) ? points1 : points2;
    u16* dst = (g < 256) ? p1t : p2t;
    const int gb = g & 255;
    const int tb = gb >> 6;
    const int n0 = (gb & 63) << 6;
    const float* sp = src + ((size_t)tb << 18);
#pragma unroll
    for (int i = 0; i < 8; i++) {
      int d = (i << 3) + (t >> 6);
      int n = t & 63;
      tile[n * 66 + d] = f2bf(sp[((size_t)d << 12) + n0 + n]);
    }
    __syncthreads();
    u16* dp = dst + ((size_t)(tb * 4096 + n0) << 6);
#pragma unroll
    for (int i = 0; i < 4; i++) {
      int n = (i << 4) + (t >> 5);
      int dp2 = t & 31;
      *(u32*)(dp + n * 64 + (dp2 << 1)) = *(const u32*)(tile + n * 66 + (dp2 << 1));
    }
  }
  __syncthreads();  // tile reads complete before candL overwrites the region

  // ---- part 2: stage candidates; SINGLE site computing s2 (r5 lesson) ----
  const int b = g >> 7;              // 512 blocks: 128 per batch
  const int rbase = (g & 127) << 5;  // 32 rows per block
  const float* X1 = xyz1 + b * 12288;
  const float* X2 = xyz2 + b * 12288;
#pragma unroll
  for (int i = 0; i < 8; i++) {
    int m = i * 512 + t;
    float x = X2[m], y = X2[4096 + m], z = X2[8192 + m];
    float s2 = __fadd_rn(__fadd_rn(__fmul_rn(x, x), __fmul_rn(y, y)),
                         __fmul_rn(z, z));
    f32x4 pk = {x, y, z, s2};
    candL[m] = pk;
  }
  __syncthreads();

  // ---- part 3: KNN, 4 rows per wave (keys[64] ONE array — r4/r10 lesson) -
#pragma unroll 1
  for (int r = 0; r < 4; r++) {
    const int n = rbase + (w << 2) + r;
    const int row = b * 4096 + n;
    const float x = X1[n], y = X1[4096 + n], z = X1[8192 + n];
    const float s1 = __fadd_rn(__fadd_rn(__fmul_rn(x, x), __fmul_rn(y, y)),
                               __fmul_rn(z, z));

    float keys[64];
    float fm = 3e38f;
#pragma unroll
    for (int j = 0; j < 64; j++) {
      const int m = (j << 6) + lane;
      f32x4 c = candL[m];
      float d = d2of(x, y, z, s1, c);
      keys[j] = d;
      fm = fminf(fm, d);
    }

    float tauf = __shfl(bitonic64f(fm, lane), 15, 64);

    // ballot+mbcnt compaction (no LDS atomics); skip empty groups
    u32 base = 0;
#pragma unroll
    for (int j = 0; j < 64; j++) {
      bool psel = keys[j] <= tauf;
      u64 mask = __ballot(psel);
      if (mask) {
        if (psel) {
          u32 pre = __builtin_amdgcn_mbcnt_lo((u32)mask, 0u);
          pre = __builtin_amdgcn_mbcnt_hi((u32)(mask >> 32), pre);
          u32 slot = base + pre;
          if (slot < 64u) {
            u64 k64 = ((u64)fkey(keys[j]) << 32) | (u32)((j << 6) + lane);
            surv[w][slot] = k64;
          }
        }
        base += (u32)__popcll(mask);
      }
    }
    u32 S = base;  // wave-uniform survivor count

    if (S <= 64) {
      u64 v = (lane < (int)S) ? surv[w][lane] : ~0ull;  // same-wave LDS order
      v = bitonic64(v, lane);
      if (lane < 16) knn[row * 16 + lane] = (int)(v & 0xFFFFFFFFull);
    } else {
      // exact cold path: increasing-order extraction from the register keys
      u64 prev = 0;
      for (int rr = 0; rr < 16; rr++) {
        u64 lm = ~0ull;
#pragma unroll
        for (int j = 0; j < 64; j++) {
          u64 k64 = ((u64)fkey(keys[j]) << 32) | (u32)((j << 6) + lane);
          if (k64 > prev && k64 < lm) lm = k64;
        }
        u64 gm = lm;
#pragma unroll
        for (int off = 32; off; off >>= 1) gm = u64min(gm, __shfl_xor(gm, off, 64));
        if (lane == 0) knn[row * 16 + rr] = (int)(gm & 0xFFFFFFFFull);
        prev = gm;
      }
    }
  }
}

// ---------------------------------------------------------------------------
// K3: fused gather + MLP + weighted reduce (verbatim r9/r13/r15 — measured
// best; r16's 2x2 retile regressed via H1 write conflicts + W L1-thrash).
// Waves split the N-dim: each wave owns 32 output channels, covers all 128
// M-rows; W slice (18 KB) L1-resident; A-fragments shared from LDS.
// ---------------------------------------------------------------------------
__global__ __launch_bounds__(256, 3) void mlp_kernel(
    const float* __restrict__ xyz1, const float* __restrict__ xyz2,
    const u16* __restrict__ p1t, const u16* __restrict__ p2t,
    const int* __restrict__ knn,
    const u16* __restrict__ W1b, const float* __restrict__ b1,
    const u16* __restrict__ W2b, const float* __restrict__ b2,
    float* __restrict__ out) {
  __shared__ __align__(16) u16 F[128 * 168];
  __shared__ __align__(16) float winv[128];
  __shared__ __align__(16) float wnorm[128];
  __shared__ __align__(16) float outbuf[128 * 12];
  const int t = threadIdx.x;
  const int g = blockIdx.x;
  const int b = g >> 9;
  const int rbase = (g & 511) << 3;

  // ---- Phase A: build F = [p1 | p2[idx] | dir | 0-pad] --------------------
  {
    const int m = t >> 1, half = t & 1;
    const int n1 = rbase + (m >> 4);
    const uint4* s1p = (const uint4*)(p1t + ((size_t)(b * 4096 + n1) << 6)) + half * 4;
    uint4* d1p = (uint4*)(F + m * 168) + half * 4;
    d1p[0] = s1p[0]; d1p[1] = s1p[1]; d1p[2] = s1p[2]; d1p[3] = s1p[3];
    const int idx = knn[(((size_t)(b * 4096 + n1)) << 4) + (m & 15)];
    const uint4* s2p = (const uint4*)(p2t + ((size_t)(b * 4096 + idx) << 6)) + half * 4;
    uint4* d2p = (uint4*)(F + m * 168 + 64) + half * 4;
    d2p[0] = s2p[0]; d2p[1] = s2p[1]; d2p[2] = s2p[2]; d2p[3] = s2p[3];
  }
  if (t < 128) {
    const int m = t;
    const int n1 = rbase + (m >> 4);
    const int idx = knn[(((size_t)(b * 4096 + n1)) << 4) + (m & 15)];
    const float* X1 = xyz1 + b * 12288;
    const float* X2 = xyz2 + b * 12288;
    float dx = X2[idx] - X1[n1];
    float dy = X2[4096 + idx] - X1[4096 + n1];
    float dz = X2[8192 + idx] - X1[8192 + n1];
    u32 u0 = (u32)f2bf(dx) | ((u32)f2bf(dy) << 16);
    u32 u1 = (u32)f2bf(dz);
    uint4 pk = make_uint4(u0, u1, 0u, 0u);
    *(uint4*)(F + m * 168 + 128) = pk;
    float d = sqrtf(dx * dx + dy * dy + dz * dz);
    winv[m] = 1.0f / fmaxf(d, 1e-10f);
  } else {
    const int m = t - 128;
    uint4 zz = make_uint4(0u, 0u, 0u, 0u);
    uint4* zp = (uint4*)(F + m * 168 + 136);
    zp[0] = zz; zp[1] = zz; zp[2] = zz; zp[3] = zz;
  }
  __syncthreads();  // barrier 1: F + winv visible

  if (t < 128) {
    const int r = t >> 4;
    float s = 0.f;
#pragma unroll
    for (int k = 0; k < 16; k++) s += winv[(r << 4) + k];
    wnorm[t] = winv[t] / s;
  }

  const int lane = t & 63;
  const int wid = t >> 6;
  const int l15 = lane & 15;
  const int quad = lane >> 4;
  const int koff = quad << 3;
  const int nbase = wid << 5;

  // ---- GEMM1 -------------------------------------------------------------
  f32x4 acc[8][2];
  const f32x4 z4 = {0.f, 0.f, 0.f, 0.f};
#pragma unroll
  for (int i = 0; i < 8; i++)
#pragma unroll
    for (int j = 0; j < 2; j++) acc[i][j] = z4;

#pragma unroll
  for (int s = 0; s < 5; s++) {
    bf16x8 bf0 = ld16(W1b + (nbase + l15) * 160 + s * 32 + koff);
    bf16x8 bf1 = ld16(W1b + (nbase + 16 + l15) * 160 + s * 32 + koff);
#pragma unroll
    for (int mt = 0; mt < 8; mt++) {
      bf16x8 a = ld16(F + (mt * 16 + l15) * 168 + s * 32 + koff);
      acc[mt][0] = MFMA16(a, bf0, acc[mt][0]);
      acc[mt][1] = MFMA16(a, bf1, acc[mt][1]);
    }
  }
  __syncthreads();  // barrier 2: GEMM1 reads done before H1 overwrite

  {
    const float bv0 = b1[nbase + l15];
    const float bv1 = b1[nbase + 16 + l15];
#pragma unroll
    for (int mt = 0; mt < 8; mt++) {
      u16* hrow = F + (mt * 16 + quad * 4) * 168;
#pragma unroll
      for (int r = 0; r < 4; r++) {
        float zv0 = acc[mt][0][r] + bv0;
        zv0 = (zv0 >= 0.f) ? zv0 : 0.1f * zv0;
        hrow[r * 168 + nbase + l15] = f2bf(zv0);
        float zv1 = acc[mt][1][r] + bv1;
        zv1 = (zv1 >= 0.f) ? zv1 : 0.1f * zv1;
        hrow[r * 168 + nbase + 16 + l15] = f2bf(zv1);
      }
    }
  }
  __syncthreads();  // barrier 3: H1 visible

  // ---- GEMM2 -------------------------------------------------------------
  f32x4 acc2[8][2];
#pragma unroll
  for (int i = 0; i < 8; i++)
#pragma unroll
    for (int j = 0; j < 2; j++) acc2[i][j] = z4;

#pragma unroll
  for (int s = 0; s < 4; s++) {
    bf16x8 bf0 = ld16(W2b + (nbase + l15) * 128 + s * 32 + koff);
    bf16x8 bf1 = ld16(W2b + (nbase + 16 + l15) * 128 + s * 32 + koff);
#pragma unroll
    for (int mt = 0; mt < 8; mt++) {
      bf16x8 a = ld16(F + (mt * 16 + l15) * 168 + s * 32 + koff);
      acc2[mt][0] = MFMA16(a, bf0, acc2[mt][0]);
      acc2[mt][1] = MFMA16(a, bf1, acc2[mt][1]);
    }
  }

  {
    const float bv0 = b2[nbase + l15];
    const float bv1 = b2[nbase + 16 + l15];
#pragma unroll
    for (int mt = 0; mt < 8; mt++) {
      const f32x4 w4 = *(const f32x4*)&wnorm[(mt << 4) + (quad << 2)];
      float p0 = 0.f, p1 = 0.f;
#pragma unroll
      for (int r = 0; r < 4; r++) {
        float zv0 = acc2[mt][0][r] + bv0;
        zv0 = (zv0 >= 0.f) ? zv0 : 0.1f * zv0;
        p0 += zv0 * w4[r];
        float zv1 = acc2[mt][1][r] + bv1;
        zv1 = (zv1 >= 0.f) ? zv1 : 0.1f * zv1;
        p1 += zv1 * w4[r];
      }
      p0 += __shfl_xor(p0, 16); p0 += __shfl_xor(p0, 32);
      p1 += __shfl_xor(p1, 16); p1 += __shfl_xor(p1, 32);
      if (quad == 0) {
        outbuf[(nbase + l15) * 12 + mt] = p0;
        outbuf[(nbase + 16 + l15) * 12 + mt] = p1;
      }
    }
  }
  __syncthreads();  // barrier 4: outbuf visible
  {
    const int ch = t >> 1, half = t & 1;
    f32x4 v = *(const f32x4*)&outbuf[ch * 12 + (half << 2)];
    float* op = out + (((size_t)(b * 128 + ch)) << 12) + rbase + (half << 2);
    *(f32x4*)op = v;
  }
}

// ---------------------------------------------------------------------------
extern "C" void kernel_launch(void* const* d_in, const int* in_sizes, int n_in,
                              void* d_out, int out_size, void* d_ws, size_t ws_size,
                              hipStream_t stream) {
  const float* xyz1 = (const float*)d_in[0];
  const float* xyz2 = (const float*)d_in[1];
  const float* points1 = (const float*)d_in[2];
  const float* points2 = (const float*)d_in[3];
  const float* W1 = (const float*)d_in[4];
  const float* b1 = (const float*)d_in[5];
  const float* W2 = (const float*)d_in[6];
  const float* b2 = (const float*)d_in[7];
  float* out = (float*)d_out;

  char* ws = (char*)d_ws;
  int* knn = (int*)ws;                        // 1,048,576 B
  u16* p1t = (u16*)(ws + 1048576);            // 2,097,152 B
  u16* p2t = (u16*)(ws + 3145728);            // 2,097,152 B
  u16* W1b = (u16*)(ws + 5242880);            // 40,960 B
  u16* W2b = (u16*)(ws + 5283840);            // 32,768 B

  hipLaunchKernelGGL(knn_prep, dim3(512), dim3(512), 0, stream,
                     xyz1, xyz2, points1, points2, W1, W2, p1t, p2t, W1b, W2b, knn);
  hipLaunchKernelGGL(mlp_kernel, dim3(2048), dim3(256), 0, stream,
                     xyz1, xyz2, p1t, p2t, knn, W1b, b1, W2b, b2, out);
}

// Round 2
// 640.397 us; speedup vs baseline: 1.4560x; 1.4560x over previous
//
#include <hip/hip_runtime.h>

typedef unsigned short u16;
typedef unsigned int u32;
typedef unsigned long long u64;
typedef __bf16 bf16x8 __attribute__((ext_vector_type(8)));
typedef float f32x4 __attribute__((ext_vector_type(4)));

#define MFMA16(a, b, c) __builtin_amdgcn_mfma_f32_16x16x32_bf16(a, b, c, 0, 0, 0)

static __device__ __forceinline__ u16 f2bf(float f) {
  union { float f; u32 u; } v; v.f = f;
  u32 u = v.u;
  u32 r = (u + 0x7FFFu + ((u >> 16) & 1u)) >> 16;  // RNE
  return (u16)r;
}

static __device__ __forceinline__ bf16x8 ld16(const u16* p) {
  return __builtin_bit_cast(bf16x8, *(const uint4*)p);
}

static __device__ __forceinline__ u64 u64min(u64 a, u64 b) { return a < b ? a : b; }

// In-wave bitonic sort of 64 u64 keys, ascending by lane.
static __device__ __forceinline__ u64 bitonic64(u64 v, int lane) {
#pragma unroll
  for (int k = 2; k <= 64; k <<= 1) {
#pragma unroll
    for (int j = k >> 1; j > 0; j >>= 1) {
      u64 o = __shfl_xor(v, j, 64);
      bool up = ((lane & k) == 0);
      bool lower = ((lane & j) == 0);
      u64 mn = v < o ? v : o;
      u64 mx = v < o ? o : v;
      v = (lower == up) ? mn : mx;
    }
  }
  return v;
}

// In-wave bitonic sort of 64 f32 (no NaN), ascending by lane.
static __device__ __forceinline__ float bitonic64f(float v, int lane) {
#pragma unroll
  for (int k = 2; k <= 64; k <<= 1) {
#pragma unroll
    for (int j = k >> 1; j > 0; j >>= 1) {
      float o = __shfl_xor(v, j, 64);
      bool up = ((lane & k) == 0);
      bool lower = ((lane & j) == 0);
      float mn = fminf(v, o);
      float mx = fmaxf(v, o);
      v = (lower == up) ? mn : mx;
    }
  }
  return v;
}

// monotone u32 key from f32 bits — pure integer transform (safe to duplicate)
static __device__ __forceinline__ u32 fkey(float f) {
  u32 bb = __float_as_uint(f);
  u32 sgn = (u32)((int)bb >> 31);
  return bb ^ (sgn | 0x80000000u);
}

// Reference fp32 distance semantics (matches np, verified r3..r16):
//   dot = fma(z,bz, fma(y,by, mul(x,bx)));  d2 = fl(fl(s1+s2) - fl(2*dot))
static __device__ __forceinline__ float d2of(float x, float y, float z, float s1,
                                             f32x4 c) {
  float dt = __builtin_fmaf(z, c[2], __builtin_fmaf(y, c[1], __fmul_rn(x, c[0])));
  return __fsub_rn(__fadd_rn(s1, c[3]), __fmul_rn(2.0f, dt));
}

// ---------------------------------------------------------------------------
// K1: PREP + KNN-16. 512-thread blocks (8 waves) share one 64 KB candL;
// 4 rows/wave at grid 512 → total rows unchanged.
// __launch_bounds__(512, 2): on THIS toolchain the 2nd arg behaves as
// CUDA-style min-BLOCKS-per-CU (round-1 evidence: arg=4 with B=512 capped
// VGPR at 64 = 512/(4blk*8waves/4simd), spilling keys[64] → 2.6 GB scratch
// traffic, 830 µs). arg=2 → 16 waves/CU → VGPR cap 128 ≥ the ~108-reg
// working set → no spill, 4 waves/SIMD (2x round-0's latency hiding).
// Inner distance/sort math is VERBATIM (exact fp32 reference semantics).
// Survivor compaction: ballot+mbcnt prefix (no LDS atomics; slot order
// differs from atomic version but bitonic sort normalizes it) with a
// wave-uniform skip of empty candidate groups. Verified correct in r1.
// ---------------------------------------------------------------------------
__global__ __launch_bounds__(512, 2) void knn_prep(
    const float* __restrict__ xyz1, const float* __restrict__ xyz2,
    const float* __restrict__ points1, const float* __restrict__ points2,
    const float* __restrict__ W1, const float* __restrict__ W2,
    u16* __restrict__ p1t, u16* __restrict__ p2t,
    u16* __restrict__ W1b, u16* __restrict__ W2b,
    int* __restrict__ knn) {
  __shared__ __align__(16) char LB[65536];
  f32x4* candL = (f32x4*)LB;     // 4096 * 16 B (knn phase)
  u16* tile = (u16*)LB;          // 64*66*2 = 8448 B (transpose phase)
  __shared__ u64 surv[8][64];    // 4 KB
  const int t = threadIdx.x;
  const int lane = t & 63;
  const int w = t >> 6;
  const int g = blockIdx.x;

  // ---- part 0: W cast (blocks 0..71, 512 threads each = 36864 items) -----
  if (g < 72) {
    int i = g * 512 + t;
    if (i < 128 * 160) {
      int r = i / 160, c = i - r * 160;
      W1b[i] = (c < 131) ? f2bf(W1[r * 131 + c]) : (u16)0;
    } else {
      int u = i - 128 * 160;
      W2b[u] = f2bf(W2[u]);
    }
  }

  // ---- part 1: one transpose tile per block (512 threads) ----------------
  {
    const float* src = (g < 256) ? points1 : points2;
    u16* dst = (g < 256) ? p1t : p2t;
    const int gb = g & 255;
    const int tb = gb >> 6;
    const int n0 = (gb & 63) << 6;
    const float* sp = src + ((size_t)tb << 18);
#pragma unroll
    for (int i = 0; i < 8; i++) {
      int d = (i << 3) + (t >> 6);
      int n = t & 63;
      tile[n * 66 + d] = f2bf(sp[((size_t)d << 12) + n0 + n]);
    }
    __syncthreads();
    u16* dp = dst + ((size_t)(tb * 4096 + n0) << 6);
#pragma unroll
    for (int i = 0; i < 4; i++) {
      int n = (i << 4) + (t >> 5);
      int dp2 = t & 31;
      *(u32*)(dp + n * 64 + (dp2 << 1)) = *(const u32*)(tile + n * 66 + (dp2 << 1));
    }
  }
  __syncthreads();  // tile reads complete before candL overwrites the region

  // ---- part 2: stage candidates; SINGLE site computing s2 (r5 lesson) ----
  const int b = g >> 7;              // 512 blocks: 128 per batch
  const int rbase = (g & 127) << 5;  // 32 rows per block
  const float* X1 = xyz1 + b * 12288;
  const float* X2 = xyz2 + b * 12288;
#pragma unroll
  for (int i = 0; i < 8; i++) {
    int m = i * 512 + t;
    float x = X2[m], y = X2[4096 + m], z = X2[8192 + m];
    float s2 = __fadd_rn(__fadd_rn(__fmul_rn(x, x), __fmul_rn(y, y)),
                         __fmul_rn(z, z));
    f32x4 pk = {x, y, z, s2};
    candL[m] = pk;
  }
  __syncthreads();

  // ---- part 3: KNN, 4 rows per wave (keys[64] ONE array — r4/r10 lesson) -
#pragma unroll 1
  for (int r = 0; r < 4; r++) {
    const int n = rbase + (w << 2) + r;
    const int row = b * 4096 + n;
    const float x = X1[n], y = X1[4096 + n], z = X1[8192 + n];
    const float s1 = __fadd_rn(__fadd_rn(__fmul_rn(x, x), __fmul_rn(y, y)),
                               __fmul_rn(z, z));

    float keys[64];
    float fm = 3e38f;
#pragma unroll
    for (int j = 0; j < 64; j++) {
      const int m = (j << 6) + lane;
      f32x4 c = candL[m];
      float d = d2of(x, y, z, s1, c);
      keys[j] = d;
      fm = fminf(fm, d);
    }

    float tauf = __shfl(bitonic64f(fm, lane), 15, 64);

    // ballot+mbcnt compaction (no LDS atomics); skip empty groups
    u32 base = 0;
#pragma unroll
    for (int j = 0; j < 64; j++) {
      bool psel = keys[j] <= tauf;
      u64 mask = __ballot(psel);
      if (mask) {
        if (psel) {
          u32 pre = __builtin_amdgcn_mbcnt_lo((u32)mask, 0u);
          pre = __builtin_amdgcn_mbcnt_hi((u32)(mask >> 32), pre);
          u32 slot = base + pre;
          if (slot < 64u) {
            u64 k64 = ((u64)fkey(keys[j]) << 32) | (u32)((j << 6) + lane);
            surv[w][slot] = k64;
          }
        }
        base += (u32)__popcll(mask);
      }
    }
    u32 S = base;  // wave-uniform survivor count

    if (S <= 64) {
      u64 v = (lane < (int)S) ? surv[w][lane] : ~0ull;  // same-wave LDS order
      v = bitonic64(v, lane);
      if (lane < 16) knn[row * 16 + lane] = (int)(v & 0xFFFFFFFFull);
    } else {
      // exact cold path: increasing-order extraction from the register keys
      u64 prev = 0;
      for (int rr = 0; rr < 16; rr++) {
        u64 lm = ~0ull;
#pragma unroll
        for (int j = 0; j < 64; j++) {
          u64 k64 = ((u64)fkey(keys[j]) << 32) | (u32)((j << 6) + lane);
          if (k64 > prev && k64 < lm) lm = k64;
        }
        u64 gm = lm;
#pragma unroll
        for (int off = 32; off; off >>= 1) gm = u64min(gm, __shfl_xor(gm, off, 64));
        if (lane == 0) knn[row * 16 + rr] = (int)(gm & 0xFFFFFFFFull);
        prev = gm;
      }
    }
  }
}

// ---------------------------------------------------------------------------
// K3: fused gather + MLP + weighted reduce (verbatim r9/r13/r15 — measured
// best; r16's 2x2 retile regressed via H1 write conflicts + W L1-thrash).
// Waves split the N-dim: each wave owns 32 output channels, covers all 128
// M-rows; W slice (18 KB) L1-resident; A-fragments shared from LDS.
// ---------------------------------------------------------------------------
__global__ __launch_bounds__(256, 3) void mlp_kernel(
    const float* __restrict__ xyz1, const float* __restrict__ xyz2,
    const u16* __restrict__ p1t, const u16* __restrict__ p2t,
    const int* __restrict__ knn,
    const u16* __restrict__ W1b, const float* __restrict__ b1,
    const u16* __restrict__ W2b, const float* __restrict__ b2,
    float* __restrict__ out) {
  __shared__ __align__(16) u16 F[128 * 168];
  __shared__ __align__(16) float winv[128];
  __shared__ __align__(16) float wnorm[128];
  __shared__ __align__(16) float outbuf[128 * 12];
  const int t = threadIdx.x;
  const int g = blockIdx.x;
  const int b = g >> 9;
  const int rbase = (g & 511) << 3;

  // ---- Phase A: build F = [p1 | p2[idx] | dir | 0-pad] --------------------
  {
    const int m = t >> 1, half = t & 1;
    const int n1 = rbase + (m >> 4);
    const uint4* s1p = (const uint4*)(p1t + ((size_t)(b * 4096 + n1) << 6)) + half * 4;
    uint4* d1p = (uint4*)(F + m * 168) + half * 4;
    d1p[0] = s1p[0]; d1p[1] = s1p[1]; d1p[2] = s1p[2]; d1p[3] = s1p[3];
    const int idx = knn[(((size_t)(b * 4096 + n1)) << 4) + (m & 15)];
    const uint4* s2p = (const uint4*)(p2t + ((size_t)(b * 4096 + idx) << 6)) + half * 4;
    uint4* d2p = (uint4*)(F + m * 168 + 64) + half * 4;
    d2p[0] = s2p[0]; d2p[1] = s2p[1]; d2p[2] = s2p[2]; d2p[3] = s2p[3];
  }
  if (t < 128) {
    const int m = t;
    const int n1 = rbase + (m >> 4);
    const int idx = knn[(((size_t)(b * 4096 + n1)) << 4) + (m & 15)];
    const float* X1 = xyz1 + b * 12288;
    const float* X2 = xyz2 + b * 12288;
    float dx = X2[idx] - X1[n1];
    float dy = X2[4096 + idx] - X1[4096 + n1];
    float dz = X2[8192 + idx] - X1[8192 + n1];
    u32 u0 = (u32)f2bf(dx) | ((u32)f2bf(dy) << 16);
    u32 u1 = (u32)f2bf(dz);
    uint4 pk = make_uint4(u0, u1, 0u, 0u);
    *(uint4*)(F + m * 168 + 128) = pk;
    float d = sqrtf(dx * dx + dy * dy + dz * dz);
    winv[m] = 1.0f / fmaxf(d, 1e-10f);
  } else {
    const int m = t - 128;
    uint4 zz = make_uint4(0u, 0u, 0u, 0u);
    uint4* zp = (uint4*)(F + m * 168 + 136);
    zp[0] = zz; zp[1] = zz; zp[2] = zz; zp[3] = zz;
  }
  __syncthreads();  // barrier 1: F + winv visible

  if (t < 128) {
    const int r = t >> 4;
    float s = 0.f;
#pragma unroll
    for (int k = 0; k < 16; k++) s += winv[(r << 4) + k];
    wnorm[t] = winv[t] / s;
  }

  const int lane = t & 63;
  const int wid = t >> 6;
  const int l15 = lane & 15;
  const int quad = lane >> 4;
  const int koff = quad << 3;
  const int nbase = wid << 5;

  // ---- GEMM1 -------------------------------------------------------------
  f32x4 acc[8][2];
  const f32x4 z4 = {0.f, 0.f, 0.f, 0.f};
#pragma unroll
  for (int i = 0; i < 8; i++)
#pragma unroll
    for (int j = 0; j < 2; j++) acc[i][j] = z4;

#pragma unroll
  for (int s = 0; s < 5; s++) {
    bf16x8 bf0 = ld16(W1b + (nbase + l15) * 160 + s * 32 + koff);
    bf16x8 bf1 = ld16(W1b + (nbase + 16 + l15) * 160 + s * 32 + koff);
#pragma unroll
    for (int mt = 0; mt < 8; mt++) {
      bf16x8 a = ld16(F + (mt * 16 + l15) * 168 + s * 32 + koff);
      acc[mt][0] = MFMA16(a, bf0, acc[mt][0]);
      acc[mt][1] = MFMA16(a, bf1, acc[mt][1]);
    }
  }
  __syncthreads();  // barrier 2: GEMM1 reads done before H1 overwrite

  {
    const float bv0 = b1[nbase + l15];
    const float bv1 = b1[nbase + 16 + l15];
#pragma unroll
    for (int mt = 0; mt < 8; mt++) {
      u16* hrow = F + (mt * 16 + quad * 4) * 168;
#pragma unroll
      for (int r = 0; r < 4; r++) {
        float zv0 = acc[mt][0][r] + bv0;
        zv0 = (zv0 >= 0.f) ? zv0 : 0.1f * zv0;
        hrow[r * 168 + nbase + l15] = f2bf(zv0);
        float zv1 = acc[mt][1][r] + bv1;
        zv1 = (zv1 >= 0.f) ? zv1 : 0.1f * zv1;
        hrow[r * 168 + nbase + 16 + l15] = f2bf(zv1);
      }
    }
  }
  __syncthreads();  // barrier 3: H1 visible

  // ---- GEMM2 -------------------------------------------------------------
  f32x4 acc2[8][2];
#pragma unroll
  for (int i = 0; i < 8; i++)
#pragma unroll
    for (int j = 0; j < 2; j++) acc2[i][j] = z4;

#pragma unroll
  for (int s = 0; s < 4; s++) {
    bf16x8 bf0 = ld16(W2b + (nbase + l15) * 128 + s * 32 + koff);
    bf16x8 bf1 = ld16(W2b + (nbase + 16 + l15) * 128 + s * 32 + koff);
#pragma unroll
    for (int mt = 0; mt < 8; mt++) {
      bf16x8 a = ld16(F + (mt * 16 + l15) * 168 + s * 32 + koff);
      acc2[mt][0] = MFMA16(a, bf0, acc2[mt][0]);
      acc2[mt][1] = MFMA16(a, bf1, acc2[mt][1]);
    }
  }

  {
    const float bv0 = b2[nbase + l15];
    const float bv1 = b2[nbase + 16 + l15];
#pragma unroll
    for (int mt = 0; mt < 8; mt++) {
      const f32x4 w4 = *(const f32x4*)&wnorm[(mt << 4) + (quad << 2)];
      float p0 = 0.f, p1 = 0.f;
#pragma unroll
      for (int r = 0; r < 4; r++) {
        float zv0 = acc2[mt][0][r] + bv0;
        zv0 = (zv0 >= 0.f) ? zv0 : 0.1f * zv0;
        p0 += zv0 * w4[r];
        float zv1 = acc2[mt][1][r] + bv1;
        zv1 = (zv1 >= 0.f) ? zv1 : 0.1f * zv1;
        p1 += zv1 * w4[r];
      }
      p0 += __shfl_xor(p0, 16); p0 += __shfl_xor(p0, 32);
      p1 += __shfl_xor(p1, 16); p1 += __shfl_xor(p1, 32);
      if (quad == 0) {
        outbuf[(nbase + l15) * 12 + mt] = p0;
        outbuf[(nbase + 16 + l15) * 12 + mt] = p1;
      }
    }
  }
  __syncthreads();  // barrier 4: outbuf visible
  {
    const int ch = t >> 1, half = t & 1;
    f32x4 v = *(const f32x4*)&outbuf[ch * 12 + (half << 2)];
    float* op = out + (((size_t)(b * 128 + ch)) << 12) + rbase + (half << 2);
    *(f32x4*)op = v;
  }
}

// ---------------------------------------------------------------------------
extern "C" void kernel_launch(void* const* d_in, const int* in_sizes, int n_in,
                              void* d_out, int out_size, void* d_ws, size_t ws_size,
                              hipStream_t stream) {
  const float* xyz1 = (const float*)d_in[0];
  const float* xyz2 = (const float*)d_in[1];
  const float* points1 = (const float*)d_in[2];
  const float* points2 = (const float*)d_in[3];
  const float* W1 = (const float*)d_in[4];
  const float* b1 = (const float*)d_in[5];
  const float* W2 = (const float*)d_in[6];
  const float* b2 = (const float*)d_in[7];
  float* out = (float*)d_out;

  char* ws = (char*)d_ws;
  int* knn = (int*)ws;                        // 1,048,576 B
  u16* p1t = (u16*)(ws + 1048576);            // 2,097,152 B
  u16* p2t = (u16*)(ws + 3145728);            // 2,097,152 B
  u16* W1b = (u16*)(ws + 5242880);            // 40,960 B
  u16* W2b = (u16*)(ws + 5283840);            // 32,768 B

  hipLaunchKernelGGL(knn_prep, dim3(512), dim3(512), 0, stream,
                     xyz1, xyz2, points1, points2, W1, W2, p1t, p2t, W1b, W2b, knn);
  hipLaunchKernelGGL(mlp_kernel, dim3(2048), dim3(256), 0, stream,
                     xyz1, xyz2, p1t, p2t, knn, W1b, b1, W2b, b2, out);
}

// Round 3
// 148.294 us; speedup vs baseline: 6.2875x; 4.3184x over previous
//
#include <hip/hip_runtime.h>

typedef unsigned short u16;
typedef unsigned int u32;
typedef unsigned long long u64;
typedef __bf16 bf16x8 __attribute__((ext_vector_type(8)));
typedef float f32x4 __attribute__((ext_vector_type(4)));

#define MFMA16(a, b, c) __builtin_amdgcn_mfma_f32_16x16x32_bf16(a, b, c, 0, 0, 0)

static __device__ __forceinline__ u16 f2bf(float f) {
  union { float f; u32 u; } v; v.f = f;
  u32 u = v.u;
  u32 r = (u + 0x7FFFu + ((u >> 16) & 1u)) >> 16;  // RNE
  return (u16)r;
}

static __device__ __forceinline__ bf16x8 ld16(const u16* p) {
  return __builtin_bit_cast(bf16x8, *(const uint4*)p);
}

static __device__ __forceinline__ u64 u64min(u64 a, u64 b) { return a < b ? a : b; }

// In-wave bitonic sort of 64 u64 keys, ascending by lane.
static __device__ __forceinline__ u64 bitonic64(u64 v, int lane) {
#pragma unroll
  for (int k = 2; k <= 64; k <<= 1) {
#pragma unroll
    for (int j = k >> 1; j > 0; j >>= 1) {
      u64 o = __shfl_xor(v, j, 64);
      bool up = ((lane & k) == 0);
      bool lower = ((lane & j) == 0);
      u64 mn = v < o ? v : o;
      u64 mx = v < o ? o : v;
      v = (lower == up) ? mn : mx;
    }
  }
  return v;
}

// In-wave bitonic sort of 64 f32 (no NaN), ascending by lane.
static __device__ __forceinline__ float bitonic64f(float v, int lane) {
#pragma unroll
  for (int k = 2; k <= 64; k <<= 1) {
#pragma unroll
    for (int j = k >> 1; j > 0; j >>= 1) {
      float o = __shfl_xor(v, j, 64);
      bool up = ((lane & k) == 0);
      bool lower = ((lane & j) == 0);
      float mn = fminf(v, o);
      float mx = fmaxf(v, o);
      v = (lower == up) ? mn : mx;
    }
  }
  return v;
}

// monotone u32 key from f32 bits — pure integer transform (safe to duplicate)
static __device__ __forceinline__ u32 fkey(float f) {
  u32 bb = __float_as_uint(f);
  u32 sgn = (u32)((int)bb >> 31);
  return bb ^ (sgn | 0x80000000u);
}

// Reference fp32 distance semantics (matches np, verified r3..r16):
//   dot = fma(z,bz, fma(y,by, mul(x,bx)));  d2 = fl(fl(s1+s2) - fl(2*dot))
// PURE function of (x,y,z,s1,c) — safe to recompute per pass, bit-identical.
static __device__ __forceinline__ float d2of(float x, float y, float z, float s1,
                                             f32x4 c) {
  float dt = __builtin_fmaf(z, c[2], __builtin_fmaf(y, c[1], __fmul_rn(x, c[0])));
  return __fsub_rn(__fadd_rn(s1, c[3]), __fmul_rn(2.0f, dt));
}

// ---------------------------------------------------------------------------
// K1: PREP + KNN-16. 512-thread blocks (8 waves) share one 64 KB candL;
// 4 rows/wave at grid 512 → total rows unchanged.
// __launch_bounds__(512, 2): 2nd arg behaves as CUDA-style min-BLOCKS-per-CU
// on this toolchain (r1 evidence: arg=4 → 64-reg cap; r2: arg=2 → 128 cap).
// r2 lesson: the keys[64] register array pushes natural demand >128 → the
// allocator pins at the cap and spills (1.66 GB scratch traffic, 475 µs).
// Fix: ELIMINATE keys[] — d2of is pure and candL is immutable during part 3,
// so each pass (min-scan, filter, cold extraction) recomputes distances from
// LDS with bit-identical fp32 results. Streaming loops use partial unroll(8)
// to bound in-flight ds_read destinations. Target: ~64-80 regs, no spill,
// 2 blocks/CU x 8 waves = 4 waves/SIMD latency hiding for the bitonic chains.
// ---------------------------------------------------------------------------
__global__ __launch_bounds__(512, 2) void knn_prep(
    const float* __restrict__ xyz1, const float* __restrict__ xyz2,
    const float* __restrict__ points1, const float* __restrict__ points2,
    const float* __restrict__ W1, const float* __restrict__ W2,
    u16* __restrict__ p1t, u16* __restrict__ p2t,
    u16* __restrict__ W1b, u16* __restrict__ W2b,
    int* __restrict__ knn) {
  __shared__ __align__(16) char LB[65536];
  f32x4* candL = (f32x4*)LB;     // 4096 * 16 B (knn phase)
  u16* tile = (u16*)LB;          // 64*66*2 = 8448 B (transpose phase)
  __shared__ u64 surv[8][64];    // 4 KB
  const int t = threadIdx.x;
  const int lane = t & 63;
  const int w = t >> 6;
  const int g = blockIdx.x;

  // ---- part 0: W cast (blocks 0..71, 512 threads each = 36864 items) -----
  if (g < 72) {
    int i = g * 512 + t;
    if (i < 128 * 160) {
      int r = i / 160, c = i - r * 160;
      W1b[i] = (c < 131) ? f2bf(W1[r * 131 + c]) : (u16)0;
    } else {
      int u = i - 128 * 160;
      W2b[u] = f2bf(W2[u]);
    }
  }

  // ---- part 1: one transpose tile per block (512 threads) ----------------
  {
    const float* src = (g < 256) ? points1 : points2;
    u16* dst = (g < 256) ? p1t : p2t;
    const int gb = g & 255;
    const int tb = gb >> 6;
    const int n0 = (gb & 63) << 6;
    const float* sp = src + ((size_t)tb << 18);
#pragma unroll
    for (int i = 0; i < 8; i++) {
      int d = (i << 3) + (t >> 6);
      int n = t & 63;
      tile[n * 66 + d] = f2bf(sp[((size_t)d << 12) + n0 + n]);
    }
    __syncthreads();
    u16* dp = dst + ((size_t)(tb * 4096 + n0) << 6);
#pragma unroll
    for (int i = 0; i < 4; i++) {
      int n = (i << 4) + (t >> 5);
      int dp2 = t & 31;
      *(u32*)(dp + n * 64 + (dp2 << 1)) = *(const u32*)(tile + n * 66 + (dp2 << 1));
    }
  }
  __syncthreads();  // tile reads complete before candL overwrites the region

  // ---- part 2: stage candidates; SINGLE site computing s2 (r5 lesson) ----
  const int b = g >> 7;              // 512 blocks: 128 per batch
  const int rbase = (g & 127) << 5;  // 32 rows per block
  const float* X1 = xyz1 + b * 12288;
  const float* X2 = xyz2 + b * 12288;
#pragma unroll
  for (int i = 0; i < 8; i++) {
    int m = i * 512 + t;
    float x = X2[m], y = X2[4096 + m], z = X2[8192 + m];
    float s2 = __fadd_rn(__fadd_rn(__fmul_rn(x, x), __fmul_rn(y, y)),
                         __fmul_rn(z, z));
    f32x4 pk = {x, y, z, s2};
    candL[m] = pk;
  }
  __syncthreads();

  // ---- part 3: KNN, 4 rows per wave, NO keys[] array (recompute passes) --
#pragma unroll 1
  for (int r = 0; r < 4; r++) {
    const int n = rbase + (w << 2) + r;
    const int row = b * 4096 + n;
    const float x = X1[n], y = X1[4096 + n], z = X1[8192 + n];
    const float s1 = __fadd_rn(__fadd_rn(__fmul_rn(x, x), __fmul_rn(y, y)),
                               __fmul_rn(z, z));

    // pass A: per-lane min over the 64 candidate groups (no stores)
    float fm = 3e38f;
#pragma unroll 8
    for (int j = 0; j < 64; j++) {
      f32x4 c = candL[(j << 6) + lane];
      fm = fminf(fm, d2of(x, y, z, s1, c));
    }

    float tauf = __shfl(bitonic64f(fm, lane), 15, 64);

    // pass B: filter via recompute; ballot+mbcnt compaction (verified r1/r2)
    u32 base = 0;
#pragma unroll 8
    for (int j = 0; j < 64; j++) {
      const int m = (j << 6) + lane;
      f32x4 c = candL[m];
      float d = d2of(x, y, z, s1, c);
      bool psel = d <= tauf;
      u64 mask = __ballot(psel);
      if (mask) {
        if (psel) {
          u32 pre = __builtin_amdgcn_mbcnt_lo((u32)mask, 0u);
          pre = __builtin_amdgcn_mbcnt_hi((u32)(mask >> 32), pre);
          u32 slot = base + pre;
          if (slot < 64u) {
            u64 k64 = ((u64)fkey(d) << 32) | (u32)m;
            surv[w][slot] = k64;
          }
        }
        base += (u32)__popcll(mask);
      }
    }
    u32 S = base;  // wave-uniform survivor count

    if (S <= 64) {
      u64 v = (lane < (int)S) ? surv[w][lane] : ~0ull;  // same-wave LDS order
      v = bitonic64(v, lane);
      if (lane < 16) knn[row * 16 + lane] = (int)(v & 0xFFFFFFFFull);
    } else {
      // exact cold path: increasing-order extraction, recomputing from candL
      u64 prev = 0;
      for (int rr = 0; rr < 16; rr++) {
        u64 lm = ~0ull;
#pragma unroll 8
        for (int j = 0; j < 64; j++) {
          const int m = (j << 6) + lane;
          f32x4 c = candL[m];
          float d = d2of(x, y, z, s1, c);
          u64 k64 = ((u64)fkey(d) << 32) | (u32)m;
          if (k64 > prev && k64 < lm) lm = k64;
        }
        u64 gm = lm;
#pragma unroll
        for (int off = 32; off; off >>= 1) gm = u64min(gm, __shfl_xor(gm, off, 64));
        if (lane == 0) knn[row * 16 + rr] = (int)(gm & 0xFFFFFFFFull);
        prev = gm;
      }
    }
  }
}

// ---------------------------------------------------------------------------
// K3: fused gather + MLP + weighted reduce (verbatim r9/r13/r15 — measured
// best; r16's 2x2 retile regressed via H1 write conflicts + W L1-thrash).
// Waves split the N-dim: each wave owns 32 output channels, covers all 128
// M-rows; W slice (18 KB) L1-resident; A-fragments shared from LDS.
// ---------------------------------------------------------------------------
__global__ __launch_bounds__(256, 3) void mlp_kernel(
    const float* __restrict__ xyz1, const float* __restrict__ xyz2,
    const u16* __restrict__ p1t, const u16* __restrict__ p2t,
    const int* __restrict__ knn,
    const u16* __restrict__ W1b, const float* __restrict__ b1,
    const u16* __restrict__ W2b, const float* __restrict__ b2,
    float* __restrict__ out) {
  __shared__ __align__(16) u16 F[128 * 168];
  __shared__ __align__(16) float winv[128];
  __shared__ __align__(16) float wnorm[128];
  __shared__ __align__(16) float outbuf[128 * 12];
  const int t = threadIdx.x;
  const int g = blockIdx.x;
  const int b = g >> 9;
  const int rbase = (g & 511) << 3;

  // ---- Phase A: build F = [p1 | p2[idx] | dir | 0-pad] --------------------
  {
    const int m = t >> 1, half = t & 1;
    const int n1 = rbase + (m >> 4);
    const uint4* s1p = (const uint4*)(p1t + ((size_t)(b * 4096 + n1) << 6)) + half * 4;
    uint4* d1p = (uint4*)(F + m * 168) + half * 4;
    d1p[0] = s1p[0]; d1p[1] = s1p[1]; d1p[2] = s1p[2]; d1p[3] = s1p[3];
    const int idx = knn[(((size_t)(b * 4096 + n1)) << 4) + (m & 15)];
    const uint4* s2p = (const uint4*)(p2t + ((size_t)(b * 4096 + idx) << 6)) + half * 4;
    uint4* d2p = (uint4*)(F + m * 168 + 64) + half * 4;
    d2p[0] = s2p[0]; d2p[1] = s2p[1]; d2p[2] = s2p[2]; d2p[3] = s2p[3];
  }
  if (t < 128) {
    const int m = t;
    const int n1 = rbase + (m >> 4);
    const int idx = knn[(((size_t)(b * 4096 + n1)) << 4) + (m & 15)];
    const float* X1 = xyz1 + b * 12288;
    const float* X2 = xyz2 + b * 12288;
    float dx = X2[idx] - X1[n1];
    float dy = X2[4096 + idx] - X1[4096 + n1];
    float dz = X2[8192 + idx] - X1[8192 + n1];
    u32 u0 = (u32)f2bf(dx) | ((u32)f2bf(dy) << 16);
    u32 u1 = (u32)f2bf(dz);
    uint4 pk = make_uint4(u0, u1, 0u, 0u);
    *(uint4*)(F + m * 168 + 128) = pk;
    float d = sqrtf(dx * dx + dy * dy + dz * dz);
    winv[m] = 1.0f / fmaxf(d, 1e-10f);
  } else {
    const int m = t - 128;
    uint4 zz = make_uint4(0u, 0u, 0u, 0u);
    uint4* zp = (uint4*)(F + m * 168 + 136);
    zp[0] = zz; zp[1] = zz; zp[2] = zz; zp[3] = zz;
  }
  __syncthreads();  // barrier 1: F + winv visible

  if (t < 128) {
    const int r = t >> 4;
    float s = 0.f;
#pragma unroll
    for (int k = 0; k < 16; k++) s += winv[(r << 4) + k];
    wnorm[t] = winv[t] / s;
  }

  const int lane = t & 63;
  const int wid = t >> 6;
  const int l15 = lane & 15;
  const int quad = lane >> 4;
  const int koff = quad << 3;
  const int nbase = wid << 5;

  // ---- GEMM1 -------------------------------------------------------------
  f32x4 acc[8][2];
  const f32x4 z4 = {0.f, 0.f, 0.f, 0.f};
#pragma unroll
  for (int i = 0; i < 8; i++)
#pragma unroll
    for (int j = 0; j < 2; j++) acc[i][j] = z4;

#pragma unroll
  for (int s = 0; s < 5; s++) {
    bf16x8 bf0 = ld16(W1b + (nbase + l15) * 160 + s * 32 + koff);
    bf16x8 bf1 = ld16(W1b + (nbase + 16 + l15) * 160 + s * 32 + koff);
#pragma unroll
    for (int mt = 0; mt < 8; mt++) {
      bf16x8 a = ld16(F + (mt * 16 + l15) * 168 + s * 32 + koff);
      acc[mt][0] = MFMA16(a, bf0, acc[mt][0]);
      acc[mt][1] = MFMA16(a, bf1, acc[mt][1]);
    }
  }
  __syncthreads();  // barrier 2: GEMM1 reads done before H1 overwrite

  {
    const float bv0 = b1[nbase + l15];
    const float bv1 = b1[nbase + 16 + l15];
#pragma unroll
    for (int mt = 0; mt < 8; mt++) {
      u16* hrow = F + (mt * 16 + quad * 4) * 168;
#pragma unroll
      for (int r = 0; r < 4; r++) {
        float zv0 = acc[mt][0][r] + bv0;
        zv0 = (zv0 >= 0.f) ? zv0 : 0.1f * zv0;
        hrow[r * 168 + nbase + l15] = f2bf(zv0);
        float zv1 = acc[mt][1][r] + bv1;
        zv1 = (zv1 >= 0.f) ? zv1 : 0.1f * zv1;
        hrow[r * 168 + nbase + 16 + l15] = f2bf(zv1);
      }
    }
  }
  __syncthreads();  // barrier 3: H1 visible

  // ---- GEMM2 -------------------------------------------------------------
  f32x4 acc2[8][2];
#pragma unroll
  for (int i = 0; i < 8; i++)
#pragma unroll
    for (int j = 0; j < 2; j++) acc2[i][j] = z4;

#pragma unroll
  for (int s = 0; s < 4; s++) {
    bf16x8 bf0 = ld16(W2b + (nbase + l15) * 128 + s * 32 + koff);
    bf16x8 bf1 = ld16(W2b + (nbase + 16 + l15) * 128 + s * 32 + koff);
#pragma unroll
    for (int mt = 0; mt < 8; mt++) {
      bf16x8 a = ld16(F + (mt * 16 + l15) * 168 + s * 32 + koff);
      acc2[mt][0] = MFMA16(a, bf0, acc2[mt][0]);
      acc2[mt][1] = MFMA16(a, bf1, acc2[mt][1]);
    }
  }

  {
    const float bv0 = b2[nbase + l15];
    const float bv1 = b2[nbase + 16 + l15];
#pragma unroll
    for (int mt = 0; mt < 8; mt++) {
      const f32x4 w4 = *(const f32x4*)&wnorm[(mt << 4) + (quad << 2)];
      float p0 = 0.f, p1 = 0.f;
#pragma unroll
      for (int r = 0; r < 4; r++) {
        float zv0 = acc2[mt][0][r] + bv0;
        zv0 = (zv0 >= 0.f) ? zv0 : 0.1f * zv0;
        p0 += zv0 * w4[r];
        float zv1 = acc2[mt][1][r] + bv1;
        zv1 = (zv1 >= 0.f) ? zv1 : 0.1f * zv1;
        p1 += zv1 * w4[r];
      }
      p0 += __shfl_xor(p0, 16); p0 += __shfl_xor(p0, 32);
      p1 += __shfl_xor(p1, 16); p1 += __shfl_xor(p1, 32);
      if (quad == 0) {
        outbuf[(nbase + l15) * 12 + mt] = p0;
        outbuf[(nbase + 16 + l15) * 12 + mt] = p1;
      }
    }
  }
  __syncthreads();  // barrier 4: outbuf visible
  {
    const int ch = t >> 1, half = t & 1;
    f32x4 v = *(const f32x4*)&outbuf[ch * 12 + (half << 2)];
    float* op = out + (((size_t)(b * 128 + ch)) << 12) + rbase + (half << 2);
    *(f32x4*)op = v;
  }
}

// ---------------------------------------------------------------------------
extern "C" void kernel_launch(void* const* d_in, const int* in_sizes, int n_in,
                              void* d_out, int out_size, void* d_ws, size_t ws_size,
                              hipStream_t stream) {
  const float* xyz1 = (const float*)d_in[0];
  const float* xyz2 = (const float*)d_in[1];
  const float* points1 = (const float*)d_in[2];
  const float* points2 = (const float*)d_in[3];
  const float* W1 = (const float*)d_in[4];
  const float* b1 = (const float*)d_in[5];
  const float* W2 = (const float*)d_in[6];
  const float* b2 = (const float*)d_in[7];
  float* out = (float*)d_out;

  char* ws = (char*)d_ws;
  int* knn = (int*)ws;                        // 1,048,576 B
  u16* p1t = (u16*)(ws + 1048576);            // 2,097,152 B
  u16* p2t = (u16*)(ws + 3145728);            // 2,097,152 B
  u16* W1b = (u16*)(ws + 5242880);            // 40,960 B
  u16* W2b = (u16*)(ws + 5283840);            // 32,768 B

  hipLaunchKernelGGL(knn_prep, dim3(512), dim3(512), 0, stream,
                     xyz1, xyz2, points1, points2, W1, W2, p1t, p2t, W1b, W2b, knn);
  hipLaunchKernelGGL(mlp_kernel, dim3(2048), dim3(256), 0, stream,
                     xyz1, xyz2, p1t, p2t, knn, W1b, b1, W2b, b2, out);
}

// Round 5
// 143.181 us; speedup vs baseline: 6.5120x; 1.0357x over previous
//
#include <hip/hip_runtime.h>

typedef unsigned short u16;
typedef unsigned int u32;
typedef unsigned long long u64;
typedef __bf16 bf16x8 __attribute__((ext_vector_type(8)));
typedef float f32x4 __attribute__((ext_vector_type(4)));

#define MFMA16(a, b, c) __builtin_amdgcn_mfma_f32_16x16x32_bf16(a, b, c, 0, 0, 0)

static __device__ __forceinline__ u16 f2bf(float f) {
  union { float f; u32 u; } v; v.f = f;
  u32 u = v.u;
  u32 r = (u + 0x7FFFu + ((u >> 16) & 1u)) >> 16;  // RNE
  return (u16)r;
}

static __device__ __forceinline__ bf16x8 ld16(const u16* p) {
  return __builtin_bit_cast(bf16x8, *(const uint4*)p);
}

static __device__ __forceinline__ u64 u64min(u64 a, u64 b) { return a < b ? a : b; }

// In-wave bitonic sort of 64 u64 keys, ascending by lane (single).
static __device__ __forceinline__ u64 bitonic64(u64 v, int lane) {
#pragma unroll
  for (int k = 2; k <= 64; k <<= 1) {
#pragma unroll
    for (int j = k >> 1; j > 0; j >>= 1) {
      u64 o = __shfl_xor(v, j, 64);
      bool up = ((lane & k) == 0);
      bool lower = ((lane & j) == 0);
      u64 mn = v < o ? v : o;
      u64 mx = v < o ? o : v;
      v = (lower == up) ? mn : mx;
    }
  }
  return v;
}

// Fused 2-wide bitonic sorts (independent values — interleaved for ILP;
// per-value op sequence identical to the single versions → same results).
static __device__ __forceinline__ void bitonic64_2(u64& a, u64& b, int lane) {
#pragma unroll
  for (int k = 2; k <= 64; k <<= 1) {
#pragma unroll
    for (int j = k >> 1; j > 0; j >>= 1) {
      u64 oa = __shfl_xor(a, j, 64);
      u64 ob = __shfl_xor(b, j, 64);
      bool up = ((lane & k) == 0);
      bool lower = ((lane & j) == 0);
      bool sel = (lower == up);
      u64 mna = a < oa ? a : oa;
      u64 mxa = a < oa ? oa : a;
      u64 mnb = b < ob ? b : ob;
      u64 mxb = b < ob ? ob : b;
      a = sel ? mna : mxa;
      b = sel ? mnb : mxb;
    }
  }
}

static __device__ __forceinline__ void bitonic64f_2(float& a, float& b, int lane) {
#pragma unroll
  for (int k = 2; k <= 64; k <<= 1) {
#pragma unroll
    for (int j = k >> 1; j > 0; j >>= 1) {
      float oa = __shfl_xor(a, j, 64);
      float ob = __shfl_xor(b, j, 64);
      bool up = ((lane & k) == 0);
      bool lower = ((lane & j) == 0);
      bool sel = (lower == up);
      float mna = fminf(a, oa), mxa = fmaxf(a, oa);
      float mnb = fminf(b, ob), mxb = fmaxf(b, ob);
      a = sel ? mna : mxa;
      b = sel ? mnb : mxb;
    }
  }
}

// monotone u32 key from f32 bits — pure integer transform (safe to duplicate)
static __device__ __forceinline__ u32 fkey(float f) {
  u32 bb = __float_as_uint(f);
  u32 sgn = (u32)((int)bb >> 31);
  return bb ^ (sgn | 0x80000000u);
}

// Reference fp32 distance semantics (matches np, verified r3..r16):
//   dot = fma(z,bz, fma(y,by, mul(x,bx)));  d2 = fl(fl(s1+s2) - fl(2*dot))
// PURE function of (x,y,z,s1,c) — safe to recompute per pass, bit-identical.
static __device__ __forceinline__ float d2of(float x, float y, float z, float s1,
                                             f32x4 c) {
  float dt = __builtin_fmaf(z, c[2], __builtin_fmaf(y, c[1], __fmul_rn(x, c[0])));
  return __fsub_rn(__fadd_rn(s1, c[3]), __fmul_rn(2.0f, dt));
}

// ---------------------------------------------------------------------------
// K1: PREP + KNN-16. 512-thread blocks (8 waves) share one 64 KB candL;
// 4 rows/wave at grid 512. __launch_bounds__(512, 2): 2nd arg is CUDA-style
// min-BLOCKS-per-CU on this toolchain (r1: arg=4 → 64-reg cap, spill;
// r2: arg=2 → 128 cap). r3: keys[] eliminated via bit-identical recompute
// passes → 52 VGPR, no spill, 49.7 µs.
// r4: ROW-PAIRING — each candL sweep (ds_read_b128) feeds TWO rows' d2of.
// LDS b128 traffic halves (was ~8192 reads/CU ≈ 41 µs of DS pipe at 12cyc —
// the r3 bottleneck candidate); the two rows' bitonic networks are fused
// 2-wide for shuffle-chain ILP. Per-row compaction order and all fp32 math
// unchanged (bit-identical). surv grows to [8][2][64] = 8 KB → 73,728 B
// total LDS, still 2 blocks/CU (≤80 KB).
// (r4 bench attempt hit "container failed twice" infra error — resubmitted
// unchanged; do not treat infra failures as kernel signal.)
// ---------------------------------------------------------------------------
__global__ __launch_bounds__(512, 2) void knn_prep(
    const float* __restrict__ xyz1, const float* __restrict__ xyz2,
    const float* __restrict__ points1, const float* __restrict__ points2,
    const float* __restrict__ W1, const float* __restrict__ W2,
    u16* __restrict__ p1t, u16* __restrict__ p2t,
    u16* __restrict__ W1b, u16* __restrict__ W2b,
    int* __restrict__ knn) {
  __shared__ __align__(16) char LB[65536];
  f32x4* candL = (f32x4*)LB;     // 4096 * 16 B (knn phase)
  u16* tile = (u16*)LB;          // 64*66*2 = 8448 B (transpose phase)
  __shared__ u64 surv[8][2][64]; // 8 KB
  const int t = threadIdx.x;
  const int lane = t & 63;
  const int w = t >> 6;
  const int g = blockIdx.x;

  // ---- part 0: W cast (blocks 0..71, 512 threads each = 36864 items) -----
  if (g < 72) {
    int i = g * 512 + t;
    if (i < 128 * 160) {
      int r = i / 160, c = i - r * 160;
      W1b[i] = (c < 131) ? f2bf(W1[r * 131 + c]) : (u16)0;
    } else {
      int u = i - 128 * 160;
      W2b[u] = f2bf(W2[u]);
    }
  }

  // ---- part 1: one transpose tile per block (512 threads) ----------------
  {
    const float* src = (g < 256) ? points1 : points2;
    u16* dst = (g < 256) ? p1t : p2t;
    const int gb = g & 255;
    const int tb = gb >> 6;
    const int n0 = (gb & 63) << 6;
    const float* sp = src + ((size_t)tb << 18);
#pragma unroll
    for (int i = 0; i < 8; i++) {
      int d = (i << 3) + (t >> 6);
      int n = t & 63;
      tile[n * 66 + d] = f2bf(sp[((size_t)d << 12) + n0 + n]);
    }
    __syncthreads();
    u16* dp = dst + ((size_t)(tb * 4096 + n0) << 6);
#pragma unroll
    for (int i = 0; i < 4; i++) {
      int n = (i << 4) + (t >> 5);
      int dp2 = t & 31;
      *(u32*)(dp + n * 64 + (dp2 << 1)) = *(const u32*)(tile + n * 66 + (dp2 << 1));
    }
  }
  __syncthreads();  // tile reads complete before candL overwrites the region

  // ---- part 2: stage candidates; SINGLE site computing s2 (r5 lesson) ----
  const int b = g >> 7;              // 512 blocks: 128 per batch
  const int rbase = (g & 127) << 5;  // 32 rows per block
  const float* X1 = xyz1 + b * 12288;
  const float* X2 = xyz2 + b * 12288;
#pragma unroll
  for (int i = 0; i < 8; i++) {
    int m = i * 512 + t;
    float x = X2[m], y = X2[4096 + m], z = X2[8192 + m];
    float s2 = __fadd_rn(__fadd_rn(__fmul_rn(x, x), __fmul_rn(y, y)),
                         __fmul_rn(z, z));
    f32x4 pk = {x, y, z, s2};
    candL[m] = pk;
  }
  __syncthreads();

  // ---- part 3: KNN, 4 rows per wave as 2 PAIRS sharing candL sweeps ------
#pragma unroll 1
  for (int pr = 0; pr < 2; pr++) {
    const int n0 = rbase + (w << 2) + (pr << 1);
    const int n1 = n0 + 1;
    const int row0 = b * 4096 + n0;
    const int row1 = row0 + 1;
    const float x0 = X1[n0], y0 = X1[4096 + n0], z0 = X1[8192 + n0];
    const float x1 = X1[n1], y1 = X1[4096 + n1], z1 = X1[8192 + n1];
    const float s10 = __fadd_rn(__fadd_rn(__fmul_rn(x0, x0), __fmul_rn(y0, y0)),
                                __fmul_rn(z0, z0));
    const float s11 = __fadd_rn(__fadd_rn(__fmul_rn(x1, x1), __fmul_rn(y1, y1)),
                                __fmul_rn(z1, z1));

    // pass A: per-lane mins for both rows off ONE candL sweep
    float fm0 = 3e38f, fm1 = 3e38f;
#pragma unroll 8
    for (int j = 0; j < 64; j++) {
      f32x4 c = candL[(j << 6) + lane];
      fm0 = fminf(fm0, d2of(x0, y0, z0, s10, c));
      fm1 = fminf(fm1, d2of(x1, y1, z1, s11, c));
    }

    bitonic64f_2(fm0, fm1, lane);
    float tau0 = __shfl(fm0, 15, 64);
    float tau1 = __shfl(fm1, 15, 64);

    // pass B: filter both rows off ONE sweep; per-row ballot+mbcnt
    // compaction (per-row j-order identical to r2/r3 verified code)
    u32 base0 = 0, base1 = 0;
#pragma unroll 8
    for (int j = 0; j < 64; j++) {
      const int m = (j << 6) + lane;
      f32x4 c = candL[m];
      float d0 = d2of(x0, y0, z0, s10, c);
      float d1 = d2of(x1, y1, z1, s11, c);
      bool p0 = d0 <= tau0;
      bool p1 = d1 <= tau1;
      u64 mk0 = __ballot(p0);
      u64 mk1 = __ballot(p1);
      if (mk0) {
        if (p0) {
          u32 pre = __builtin_amdgcn_mbcnt_lo((u32)mk0, 0u);
          pre = __builtin_amdgcn_mbcnt_hi((u32)(mk0 >> 32), pre);
          u32 slot = base0 + pre;
          if (slot < 64u) surv[w][0][slot] = ((u64)fkey(d0) << 32) | (u32)m;
        }
        base0 += (u32)__popcll(mk0);
      }
      if (mk1) {
        if (p1) {
          u32 pre = __builtin_amdgcn_mbcnt_lo((u32)mk1, 0u);
          pre = __builtin_amdgcn_mbcnt_hi((u32)(mk1 >> 32), pre);
          u32 slot = base1 + pre;
          if (slot < 64u) surv[w][1][slot] = ((u64)fkey(d1) << 32) | (u32)m;
        }
        base1 += (u32)__popcll(mk1);
      }
    }
    const u32 S0 = base0, S1 = base1;  // wave-uniform

    if (S0 <= 64 && S1 <= 64) {
      u64 v0 = (lane < (int)S0) ? surv[w][0][lane] : ~0ull;
      u64 v1 = (lane < (int)S1) ? surv[w][1][lane] : ~0ull;
      bitonic64_2(v0, v1, lane);
      if (lane < 16) {
        knn[row0 * 16 + lane] = (int)(v0 & 0xFFFFFFFFull);
        knn[row1 * 16 + lane] = (int)(v1 & 0xFFFFFFFFull);
      }
    } else {
      // rare: handle each row independently (hot single-sort or exact cold)
#pragma unroll 1
      for (int p = 0; p < 2; p++) {
        const u32 S = p ? S1 : S0;
        const int row = p ? row1 : row0;
        const float xx = p ? x1 : x0, yy = p ? y1 : y0, zz = p ? z1 : z0;
        const float ss = p ? s11 : s10;
        if (S <= 64) {
          u64 v = (lane < (int)S) ? surv[w][p][lane] : ~0ull;
          v = bitonic64(v, lane);
          if (lane < 16) knn[row * 16 + lane] = (int)(v & 0xFFFFFFFFull);
        } else {
          // exact cold path: increasing-order extraction, recompute from candL
          u64 prev = 0;
          for (int rr = 0; rr < 16; rr++) {
            u64 lm = ~0ull;
#pragma unroll 8
            for (int j = 0; j < 64; j++) {
              const int m = (j << 6) + lane;
              f32x4 c = candL[m];
              float d = d2of(xx, yy, zz, ss, c);
              u64 k64 = ((u64)fkey(d) << 32) | (u32)m;
              if (k64 > prev && k64 < lm) lm = k64;
            }
            u64 gm = lm;
#pragma unroll
            for (int off = 32; off; off >>= 1)
              gm = u64min(gm, __shfl_xor(gm, off, 64));
            if (lane == 0) knn[row * 16 + rr] = (int)(gm & 0xFFFFFFFFull);
            prev = gm;
          }
        }
      }
    }
  }
}

// ---------------------------------------------------------------------------
// K3: fused gather + MLP + weighted reduce (verbatim r9/r13/r15 — measured
// best; r16's 2x2 retile regressed via H1 write conflicts + W L1-thrash).
// Waves split the N-dim: each wave owns 32 output channels, covers all 128
// M-rows; W slice (18 KB) L1-resident; A-fragments shared from LDS.
// ---------------------------------------------------------------------------
__global__ __launch_bounds__(256, 3) void mlp_kernel(
    const float* __restrict__ xyz1, const float* __restrict__ xyz2,
    const u16* __restrict__ p1t, const u16* __restrict__ p2t,
    const int* __restrict__ knn,
    const u16* __restrict__ W1b, const float* __restrict__ b1,
    const u16* __restrict__ W2b, const float* __restrict__ b2,
    float* __restrict__ out) {
  __shared__ __align__(16) u16 F[128 * 168];
  __shared__ __align__(16) float winv[128];
  __shared__ __align__(16) float wnorm[128];
  __shared__ __align__(16) float outbuf[128 * 12];
  const int t = threadIdx.x;
  const int g = blockIdx.x;
  const int b = g >> 9;
  const int rbase = (g & 511) << 3;

  // ---- Phase A: build F = [p1 | p2[idx] | dir | 0-pad] --------------------
  {
    const int m = t >> 1, half = t & 1;
    const int n1 = rbase + (m >> 4);
    const uint4* s1p = (const uint4*)(p1t + ((size_t)(b * 4096 + n1) << 6)) + half * 4;
    uint4* d1p = (uint4*)(F + m * 168) + half * 4;
    d1p[0] = s1p[0]; d1p[1] = s1p[1]; d1p[2] = s1p[2]; d1p[3] = s1p[3];
    const int idx = knn[(((size_t)(b * 4096 + n1)) << 4) + (m & 15)];
    const uint4* s2p = (const uint4*)(p2t + ((size_t)(b * 4096 + idx) << 6)) + half * 4;
    uint4* d2p = (uint4*)(F + m * 168 + 64) + half * 4;
    d2p[0] = s2p[0]; d2p[1] = s2p[1]; d2p[2] = s2p[2]; d2p[3] = s2p[3];
  }
  if (t < 128) {
    const int m = t;
    const int n1 = rbase + (m >> 4);
    const int idx = knn[(((size_t)(b * 4096 + n1)) << 4) + (m & 15)];
    const float* X1 = xyz1 + b * 12288;
    const float* X2 = xyz2 + b * 12288;
    float dx = X2[idx] - X1[n1];
    float dy = X2[4096 + idx] - X1[4096 + n1];
    float dz = X2[8192 + idx] - X1[8192 + n1];
    u32 u0 = (u32)f2bf(dx) | ((u32)f2bf(dy) << 16);
    u32 u1 = (u32)f2bf(dz);
    uint4 pk = make_uint4(u0, u1, 0u, 0u);
    *(uint4*)(F + m * 168 + 128) = pk;
    float d = sqrtf(dx * dx + dy * dy + dz * dz);
    winv[m] = 1.0f / fmaxf(d, 1e-10f);
  } else {
    const int m = t - 128;
    uint4 zz = make_uint4(0u, 0u, 0u, 0u);
    uint4* zp = (uint4*)(F + m * 168 + 136);
    zp[0] = zz; zp[1] = zz; zp[2] = zz; zp[3] = zz;
  }
  __syncthreads();  // barrier 1: F + winv visible

  if (t < 128) {
    const int r = t >> 4;
    float s = 0.f;
#pragma unroll
    for (int k = 0; k < 16; k++) s += winv[(r << 4) + k];
    wnorm[t] = winv[t] / s;
  }

  const int lane = t & 63;
  const int wid = t >> 6;
  const int l15 = lane & 15;
  const int quad = lane >> 4;
  const int koff = quad << 3;
  const int nbase = wid << 5;

  // ---- GEMM1 -------------------------------------------------------------
  f32x4 acc[8][2];
  const f32x4 z4 = {0.f, 0.f, 0.f, 0.f};
#pragma unroll
  for (int i = 0; i < 8; i++)
#pragma unroll
    for (int j = 0; j < 2; j++) acc[i][j] = z4;

#pragma unroll
  for (int s = 0; s < 5; s++) {
    bf16x8 bf0 = ld16(W1b + (nbase + l15) * 160 + s * 32 + koff);
    bf16x8 bf1 = ld16(W1b + (nbase + 16 + l15) * 160 + s * 32 + koff);
#pragma unroll
    for (int mt = 0; mt < 8; mt++) {
      bf16x8 a = ld16(F + (mt * 16 + l15) * 168 + s * 32 + koff);
      acc[mt][0] = MFMA16(a, bf0, acc[mt][0]);
      acc[mt][1] = MFMA16(a, bf1, acc[mt][1]);
    }
  }
  __syncthreads();  // barrier 2: GEMM1 reads done before H1 overwrite

  {
    const float bv0 = b1[nbase + l15];
    const float bv1 = b1[nbase + 16 + l15];
#pragma unroll
    for (int mt = 0; mt < 8; mt++) {
      u16* hrow = F + (mt * 16 + quad * 4) * 168;
#pragma unroll
      for (int r = 0; r < 4; r++) {
        float zv0 = acc[mt][0][r] + bv0;
        zv0 = (zv0 >= 0.f) ? zv0 : 0.1f * zv0;
        hrow[r * 168 + nbase + l15] = f2bf(zv0);
        float zv1 = acc[mt][1][r] + bv1;
        zv1 = (zv1 >= 0.f) ? zv1 : 0.1f * zv1;
        hrow[r * 168 + nbase + 16 + l15] = f2bf(zv1);
      }
    }
  }
  __syncthreads();  // barrier 3: H1 visible

  // ---- GEMM2 -------------------------------------------------------------
  f32x4 acc2[8][2];
#pragma unroll
  for (int i = 0; i < 8; i++)
#pragma unroll
    for (int j = 0; j < 2; j++) acc2[i][j] = z4;

#pragma unroll
  for (int s = 0; s < 4; s++) {
    bf16x8 bf0 = ld16(W2b + (nbase + l15) * 128 + s * 32 + koff);
    bf16x8 bf1 = ld16(W2b + (nbase + 16 + l15) * 128 + s * 32 + koff);
#pragma unroll
    for (int mt = 0; mt < 8; mt++) {
      bf16x8 a = ld16(F + (mt * 16 + l15) * 168 + s * 32 + koff);
      acc2[mt][0] = MFMA16(a, bf0, acc2[mt][0]);
      acc2[mt][1] = MFMA16(a, bf1, acc2[mt][1]);
    }
  }

  {
    const float bv0 = b2[nbase + l15];
    const float bv1 = b2[nbase + 16 + l15];
#pragma unroll
    for (int mt = 0; mt < 8; mt++) {
      const f32x4 w4 = *(const f32x4*)&wnorm[(mt << 4) + (quad << 2)];
      float p0 = 0.f, p1 = 0.f;
#pragma unroll
      for (int r = 0; r < 4; r++) {
        float zv0 = acc2[mt][0][r] + bv0;
        zv0 = (zv0 >= 0.f) ? zv0 : 0.1f * zv0;
        p0 += zv0 * w4[r];
        float zv1 = acc2[mt][1][r] + bv1;
        zv1 = (zv1 >= 0.f) ? zv1 : 0.1f * zv1;
        p1 += zv1 * w4[r];
      }
      p0 += __shfl_xor(p0, 16); p0 += __shfl_xor(p0, 32);
      p1 += __shfl_xor(p1, 16); p1 += __shfl_xor(p1, 32);
      if (quad == 0) {
        outbuf[(nbase + l15) * 12 + mt] = p0;
        outbuf[(nbase + 16 + l15) * 12 + mt] = p1;
      }
    }
  }
  __syncthreads();  // barrier 4: outbuf visible
  {
    const int ch = t >> 1, half = t & 1;
    f32x4 v = *(const f32x4*)&outbuf[ch * 12 + (half << 2)];
    float* op = out + (((size_t)(b * 128 + ch)) << 12) + rbase + (half << 2);
    *(f32x4*)op = v;
  }
}

// ---------------------------------------------------------------------------
extern "C" void kernel_launch(void* const* d_in, const int* in_sizes, int n_in,
                              void* d_out, int out_size, void* d_ws, size_t ws_size,
                              hipStream_t stream) {
  const float* xyz1 = (const float*)d_in[0];
  const float* xyz2 = (const float*)d_in[1];
  const float* points1 = (const float*)d_in[2];
  const float* points2 = (const float*)d_in[3];
  const float* W1 = (const float*)d_in[4];
  const float* b1 = (const float*)d_in[5];
  const float* W2 = (const float*)d_in[6];
  const float* b2 = (const float*)d_in[7];
  float* out = (float*)d_out;

  char* ws = (char*)d_ws;
  int* knn = (int*)ws;                        // 1,048,576 B
  u16* p1t = (u16*)(ws + 1048576);            // 2,097,152 B
  u16* p2t = (u16*)(ws + 3145728);            // 2,097,152 B
  u16* W1b = (u16*)(ws + 5242880);            // 40,960 B
  u16* W2b = (u16*)(ws + 5283840);            // 32,768 B

  hipLaunchKernelGGL(knn_prep, dim3(512), dim3(512), 0, stream,
                     xyz1, xyz2, points1, points2, W1, W2, p1t, p2t, W1b, W2b, knn);
  hipLaunchKernelGGL(mlp_kernel, dim3(2048), dim3(256), 0, stream,
                     xyz1, xyz2, p1t, p2t, knn, W1b, b1, W2b, b2, out);
}

// Round 6
// 141.442 us; speedup vs baseline: 6.5921x; 1.0123x over previous
//
#include <hip/hip_runtime.h>

typedef unsigned short u16;
typedef unsigned int u32;
typedef unsigned long long u64;
typedef __bf16 bf16x8 __attribute__((ext_vector_type(8)));
typedef float f32x4 __attribute__((ext_vector_type(4)));

#define MFMA16(a, b, c) __builtin_amdgcn_mfma_f32_16x16x32_bf16(a, b, c, 0, 0, 0)

static __device__ __forceinline__ u16 f2bf(float f) {
  union { float f; u32 u; } v; v.f = f;
  u32 u = v.u;
  u32 r = (u + 0x7FFFu + ((u >> 16) & 1u)) >> 16;  // RNE
  return (u16)r;
}

static __device__ __forceinline__ bf16x8 ld16(const u16* p) {
  return __builtin_bit_cast(bf16x8, *(const uint4*)p);
}

static __device__ __forceinline__ u64 u64min(u64 a, u64 b) { return a < b ? a : b; }

// In-wave bitonic sort of 64 u64 keys, ascending by lane (single).
static __device__ __forceinline__ u64 bitonic64(u64 v, int lane) {
#pragma unroll
  for (int k = 2; k <= 64; k <<= 1) {
#pragma unroll
    for (int j = k >> 1; j > 0; j >>= 1) {
      u64 o = __shfl_xor(v, j, 64);
      bool up = ((lane & k) == 0);
      bool lower = ((lane & j) == 0);
      u64 mn = v < o ? v : o;
      u64 mx = v < o ? o : v;
      v = (lower == up) ? mn : mx;
    }
  }
  return v;
}

// Fused 4-wide bitonic sorts (independent values — interleaved for shuffle
// ILP; per-value op sequence identical to the single version → same results).
static __device__ __forceinline__ void bitonic64_4(u64& a, u64& b, u64& c,
                                                   u64& d, int lane) {
#pragma unroll
  for (int k = 2; k <= 64; k <<= 1) {
#pragma unroll
    for (int j = k >> 1; j > 0; j >>= 1) {
      u64 oa = __shfl_xor(a, j, 64);
      u64 ob = __shfl_xor(b, j, 64);
      u64 oc = __shfl_xor(c, j, 64);
      u64 od = __shfl_xor(d, j, 64);
      bool up = ((lane & k) == 0);
      bool lower = ((lane & j) == 0);
      bool sel = (lower == up);
      u64 mna = a < oa ? a : oa, mxa = a < oa ? oa : a;
      u64 mnb = b < ob ? b : ob, mxb = b < ob ? ob : b;
      u64 mnc = c < oc ? c : oc, mxc = c < oc ? oc : c;
      u64 mnd = d < od ? d : od, mxd = d < od ? od : d;
      a = sel ? mna : mxa;
      b = sel ? mnb : mxb;
      c = sel ? mnc : mxc;
      d = sel ? mnd : mxd;
    }
  }
}

static __device__ __forceinline__ void bitonic64f_4(float& a, float& b,
                                                    float& c, float& d,
                                                    int lane) {
#pragma unroll
  for (int k = 2; k <= 64; k <<= 1) {
#pragma unroll
    for (int j = k >> 1; j > 0; j >>= 1) {
      float oa = __shfl_xor(a, j, 64);
      float ob = __shfl_xor(b, j, 64);
      float oc = __shfl_xor(c, j, 64);
      float od = __shfl_xor(d, j, 64);
      bool up = ((lane & k) == 0);
      bool lower = ((lane & j) == 0);
      bool sel = (lower == up);
      float mna = fminf(a, oa), mxa = fmaxf(a, oa);
      float mnb = fminf(b, ob), mxb = fmaxf(b, ob);
      float mnc = fminf(c, oc), mxc = fmaxf(c, oc);
      float mnd = fminf(d, od), mxd = fmaxf(d, od);
      a = sel ? mna : mxa;
      b = sel ? mnb : mxb;
      c = sel ? mnc : mxc;
      d = sel ? mnd : mxd;
    }
  }
}

// monotone u32 key from f32 bits — pure integer transform (safe to duplicate)
static __device__ __forceinline__ u32 fkey(float f) {
  u32 bb = __float_as_uint(f);
  u32 sgn = (u32)((int)bb >> 31);
  return bb ^ (sgn | 0x80000000u);
}

// Reference fp32 distance semantics (matches np, verified r3..r16):
//   dot = fma(z,bz, fma(y,by, mul(x,bx)));  d2 = fl(fl(s1+s2) - fl(2*dot))
// PURE function of (x,y,z,s1,c) — safe to recompute per pass, bit-identical.
static __device__ __forceinline__ float d2of(float x, float y, float z, float s1,
                                             f32x4 c) {
  float dt = __builtin_fmaf(z, c[2], __builtin_fmaf(y, c[1], __fmul_rn(x, c[0])));
  return __fsub_rn(__fadd_rn(s1, c[3]), __fmul_rn(2.0f, dt));
}

// ---------------------------------------------------------------------------
// K1: PREP + KNN-16. 512-thread blocks (8 waves) share one 64 KB candL.
// __launch_bounds__(512, 2): 2nd arg is CUDA-style min-BLOCKS-per-CU on this
// toolchain (r1: arg=4 → 64-reg cap, spill; r2: arg=2 → 128 cap).
// r3: keys[] eliminated via bit-identical recompute passes → 52 VGPR, 49.7µs.
// r5: row-pairing (one sweep feeds 2 rows) → 44.2 µs; post-mortem arithmetic:
// DS pipe ≈ 20µs reads + ~8µs bpermute (shuffles ARE DS ops), VALU ≈ 26µs.
// r6: QUAD-SHARING — one candL sweep feeds all 4 of the wave's rows. DS
// candidate reads halve again (→~10µs); all 4 bitonic networks fuse 4-wide
// (4 independent shuffle chains interleaved → latency amortized). Per-row
// compaction order and fp32 math unchanged (bit-identical). surv[8][4][64]
// = 16 KB → 81,920 B/block; 2 × 81,920 = 163,840 = exactly 160 KiB/CU
// (measured LDS_Block_Size has always been exactly-as-declared, no padding).
// REVERT TRIGGER: occupancy ~halves or dur > 44 µs → exact-fit failed,
// shrink surv depth to 48.
// ---------------------------------------------------------------------------
__global__ __launch_bounds__(512, 2) void knn_prep(
    const float* __restrict__ xyz1, const float* __restrict__ xyz2,
    const float* __restrict__ points1, const float* __restrict__ points2,
    const float* __restrict__ W1, const float* __restrict__ W2,
    u16* __restrict__ p1t, u16* __restrict__ p2t,
    u16* __restrict__ W1b, u16* __restrict__ W2b,
    int* __restrict__ knn) {
  __shared__ __align__(16) char LB[65536];
  f32x4* candL = (f32x4*)LB;     // 4096 * 16 B (knn phase)
  u16* tile = (u16*)LB;          // 64*66*2 = 8448 B (transpose phase)
  __shared__ u64 surv[8][4][64]; // 16 KB
  const int t = threadIdx.x;
  const int lane = t & 63;
  const int w = t >> 6;
  const int g = blockIdx.x;

  // ---- part 0: W cast (blocks 0..71, 512 threads each = 36864 items) -----
  if (g < 72) {
    int i = g * 512 + t;
    if (i < 128 * 160) {
      int r = i / 160, c = i - r * 160;
      W1b[i] = (c < 131) ? f2bf(W1[r * 131 + c]) : (u16)0;
    } else {
      int u = i - 128 * 160;
      W2b[u] = f2bf(W2[u]);
    }
  }

  // ---- part 1: one transpose tile per block (512 threads) ----------------
  {
    const float* src = (g < 256) ? points1 : points2;
    u16* dst = (g < 256) ? p1t : p2t;
    const int gb = g & 255;
    const int tb = gb >> 6;
    const int n0 = (gb & 63) << 6;
    const float* sp = src + ((size_t)tb << 18);
#pragma unroll
    for (int i = 0; i < 8; i++) {
      int d = (i << 3) + (t >> 6);
      int n = t & 63;
      tile[n * 66 + d] = f2bf(sp[((size_t)d << 12) + n0 + n]);
    }
    __syncthreads();
    u16* dp = dst + ((size_t)(tb * 4096 + n0) << 6);
#pragma unroll
    for (int i = 0; i < 4; i++) {
      int n = (i << 4) + (t >> 5);
      int dp2 = t & 31;
      *(u32*)(dp + n * 64 + (dp2 << 1)) = *(const u32*)(tile + n * 66 + (dp2 << 1));
    }
  }
  __syncthreads();  // tile reads complete before candL overwrites the region

  // ---- part 2: stage candidates; SINGLE site computing s2 (r5 lesson) ----
  const int b = g >> 7;              // 512 blocks: 128 per batch
  const int rbase = (g & 127) << 5;  // 32 rows per block
  const float* X1 = xyz1 + b * 12288;
  const float* X2 = xyz2 + b * 12288;
#pragma unroll
  for (int i = 0; i < 8; i++) {
    int m = i * 512 + t;
    float x = X2[m], y = X2[4096 + m], z = X2[8192 + m];
    float s2 = __fadd_rn(__fadd_rn(__fmul_rn(x, x), __fmul_rn(y, y)),
                         __fmul_rn(z, z));
    f32x4 pk = {x, y, z, s2};
    candL[m] = pk;
  }
  __syncthreads();

  // ---- part 3: KNN — one QUAD: all 4 wave rows share each candL sweep ----
  {
    const int nq = rbase + (w << 2);
    const int rowq = b * 4096 + nq;
    const float x0 = X1[nq + 0], y0 = X1[4096 + nq + 0], z0 = X1[8192 + nq + 0];
    const float x1 = X1[nq + 1], y1 = X1[4096 + nq + 1], z1 = X1[8192 + nq + 1];
    const float x2 = X1[nq + 2], y2 = X1[4096 + nq + 2], z2 = X1[8192 + nq + 2];
    const float x3 = X1[nq + 3], y3 = X1[4096 + nq + 3], z3 = X1[8192 + nq + 3];
    const float s0 = __fadd_rn(__fadd_rn(__fmul_rn(x0, x0), __fmul_rn(y0, y0)),
                               __fmul_rn(z0, z0));
    const float s1 = __fadd_rn(__fadd_rn(__fmul_rn(x1, x1), __fmul_rn(y1, y1)),
                               __fmul_rn(z1, z1));
    const float s2 = __fadd_rn(__fadd_rn(__fmul_rn(x2, x2), __fmul_rn(y2, y2)),
                               __fmul_rn(z2, z2));
    const float s3 = __fadd_rn(__fadd_rn(__fmul_rn(x3, x3), __fmul_rn(y3, y3)),
                               __fmul_rn(z3, z3));

    // pass A: per-lane mins for all 4 rows off ONE candL sweep
    float fm0 = 3e38f, fm1 = 3e38f, fm2 = 3e38f, fm3 = 3e38f;
#pragma unroll 8
    for (int j = 0; j < 64; j++) {
      f32x4 c = candL[(j << 6) + lane];
      fm0 = fminf(fm0, d2of(x0, y0, z0, s0, c));
      fm1 = fminf(fm1, d2of(x1, y1, z1, s1, c));
      fm2 = fminf(fm2, d2of(x2, y2, z2, s2, c));
      fm3 = fminf(fm3, d2of(x3, y3, z3, s3, c));
    }

    bitonic64f_4(fm0, fm1, fm2, fm3, lane);
    const float tau0 = __shfl(fm0, 15, 64);
    const float tau1 = __shfl(fm1, 15, 64);
    const float tau2 = __shfl(fm2, 15, 64);
    const float tau3 = __shfl(fm3, 15, 64);

    // pass B: filter all 4 rows off ONE sweep; per-row ballot+mbcnt
    // compaction (per-row j-order identical to r2..r5 verified code)
    u32 base0 = 0, base1 = 0, base2 = 0, base3 = 0;
#pragma unroll 4
    for (int j = 0; j < 64; j++) {
      const int m = (j << 6) + lane;
      f32x4 c = candL[m];
      float d0 = d2of(x0, y0, z0, s0, c);
      float d1 = d2of(x1, y1, z1, s1, c);
      float d2 = d2of(x2, y2, z2, s2, c);
      float d3 = d2of(x3, y3, z3, s3, c);
      bool p0 = d0 <= tau0;
      bool p1 = d1 <= tau1;
      bool p2 = d2 <= tau2;
      bool p3 = d3 <= tau3;
      u64 mk0 = __ballot(p0);
      u64 mk1 = __ballot(p1);
      u64 mk2 = __ballot(p2);
      u64 mk3 = __ballot(p3);
      if (mk0) {
        if (p0) {
          u32 pre = __builtin_amdgcn_mbcnt_lo((u32)mk0, 0u);
          pre = __builtin_amdgcn_mbcnt_hi((u32)(mk0 >> 32), pre);
          u32 slot = base0 + pre;
          if (slot < 64u) surv[w][0][slot] = ((u64)fkey(d0) << 32) | (u32)m;
        }
        base0 += (u32)__popcll(mk0);
      }
      if (mk1) {
        if (p1) {
          u32 pre = __builtin_amdgcn_mbcnt_lo((u32)mk1, 0u);
          pre = __builtin_amdgcn_mbcnt_hi((u32)(mk1 >> 32), pre);
          u32 slot = base1 + pre;
          if (slot < 64u) surv[w][1][slot] = ((u64)fkey(d1) << 32) | (u32)m;
        }
        base1 += (u32)__popcll(mk1);
      }
      if (mk2) {
        if (p2) {
          u32 pre = __builtin_amdgcn_mbcnt_lo((u32)mk2, 0u);
          pre = __builtin_amdgcn_mbcnt_hi((u32)(mk2 >> 32), pre);
          u32 slot = base2 + pre;
          if (slot < 64u) surv[w][2][slot] = ((u64)fkey(d2) << 32) | (u32)m;
        }
        base2 += (u32)__popcll(mk2);
      }
      if (mk3) {
        if (p3) {
          u32 pre = __builtin_amdgcn_mbcnt_lo((u32)mk3, 0u);
          pre = __builtin_amdgcn_mbcnt_hi((u32)(mk3 >> 32), pre);
          u32 slot = base3 + pre;
          if (slot < 64u) surv[w][3][slot] = ((u64)fkey(d3) << 32) | (u32)m;
        }
        base3 += (u32)__popcll(mk3);
      }
    }
    const u32 S0 = base0, S1 = base1, S2 = base2, S3 = base3;  // wave-uniform

    if (S0 <= 64 && S1 <= 64 && S2 <= 64 && S3 <= 64) {
      u64 v0 = (lane < (int)S0) ? surv[w][0][lane] : ~0ull;
      u64 v1 = (lane < (int)S1) ? surv[w][1][lane] : ~0ull;
      u64 v2 = (lane < (int)S2) ? surv[w][2][lane] : ~0ull;
      u64 v3 = (lane < (int)S3) ? surv[w][3][lane] : ~0ull;
      bitonic64_4(v0, v1, v2, v3, lane);
      if (lane < 16) {
        knn[(rowq + 0) * 16 + lane] = (int)(v0 & 0xFFFFFFFFull);
        knn[(rowq + 1) * 16 + lane] = (int)(v1 & 0xFFFFFFFFull);
        knn[(rowq + 2) * 16 + lane] = (int)(v2 & 0xFFFFFFFFull);
        knn[(rowq + 3) * 16 + lane] = (int)(v3 & 0xFFFFFFFFull);
      }
    } else {
      // rare: handle each row independently (hot single-sort or exact cold).
      // Row state selected via cndmask chains — NO runtime-indexed arrays.
#pragma unroll 1
      for (int p = 0; p < 4; p++) {
        const u32 S = (p & 2) ? ((p & 1) ? S3 : S2) : ((p & 1) ? S1 : S0);
        const int row = rowq + p;
        const float xx = (p & 2) ? ((p & 1) ? x3 : x2) : ((p & 1) ? x1 : x0);
        const float yy = (p & 2) ? ((p & 1) ? y3 : y2) : ((p & 1) ? y1 : y0);
        const float zz = (p & 2) ? ((p & 1) ? z3 : z2) : ((p & 1) ? z1 : z0);
        const float ss = (p & 2) ? ((p & 1) ? s3 : s2) : ((p & 1) ? s1 : s0);
        if (S <= 64) {
          u64 v = (lane < (int)S) ? surv[w][p][lane] : ~0ull;
          v = bitonic64(v, lane);
          if (lane < 16) knn[row * 16 + lane] = (int)(v & 0xFFFFFFFFull);
        } else {
          // exact cold path: increasing-order extraction, recompute from candL
          u64 prev = 0;
          for (int rr = 0; rr < 16; rr++) {
            u64 lm = ~0ull;
#pragma unroll 8
            for (int j = 0; j < 64; j++) {
              const int m = (j << 6) + lane;
              f32x4 c = candL[m];
              float d = d2of(xx, yy, zz, ss, c);
              u64 k64 = ((u64)fkey(d) << 32) | (u32)m;
              if (k64 > prev && k64 < lm) lm = k64;
            }
            u64 gm = lm;
#pragma unroll
            for (int off = 32; off; off >>= 1)
              gm = u64min(gm, __shfl_xor(gm, off, 64));
            if (lane == 0) knn[row * 16 + rr] = (int)(gm & 0xFFFFFFFFull);
            prev = gm;
          }
        }
      }
    }
  }
}

// ---------------------------------------------------------------------------
// K3: fused gather + MLP + weighted reduce (verbatim r9/r13/r15 — measured
// best; r16's 2x2 retile regressed via H1 write conflicts + W L1-thrash).
// Waves split the N-dim: each wave owns 32 output channels, covers all 128
// M-rows; W slice (18 KB) L1-resident; A-fragments shared from LDS.
// ---------------------------------------------------------------------------
__global__ __launch_bounds__(256, 3) void mlp_kernel(
    const float* __restrict__ xyz1, const float* __restrict__ xyz2,
    const u16* __restrict__ p1t, const u16* __restrict__ p2t,
    const int* __restrict__ knn,
    const u16* __restrict__ W1b, const float* __restrict__ b1,
    const u16* __restrict__ W2b, const float* __restrict__ b2,
    float* __restrict__ out) {
  __shared__ __align__(16) u16 F[128 * 168];
  __shared__ __align__(16) float winv[128];
  __shared__ __align__(16) float wnorm[128];
  __shared__ __align__(16) float outbuf[128 * 12];
  const int t = threadIdx.x;
  const int g = blockIdx.x;
  const int b = g >> 9;
  const int rbase = (g & 511) << 3;

  // ---- Phase A: build F = [p1 | p2[idx] | dir | 0-pad] --------------------
  {
    const int m = t >> 1, half = t & 1;
    const int n1 = rbase + (m >> 4);
    const uint4* s1p = (const uint4*)(p1t + ((size_t)(b * 4096 + n1) << 6)) + half * 4;
    uint4* d1p = (uint4*)(F + m * 168) + half * 4;
    d1p[0] = s1p[0]; d1p[1] = s1p[1]; d1p[2] = s1p[2]; d1p[3] = s1p[3];
    const int idx = knn[(((size_t)(b * 4096 + n1)) << 4) + (m & 15)];
    const uint4* s2p = (const uint4*)(p2t + ((size_t)(b * 4096 + idx) << 6)) + half * 4;
    uint4* d2p = (uint4*)(F + m * 168 + 64) + half * 4;
    d2p[0] = s2p[0]; d2p[1] = s2p[1]; d2p[2] = s2p[2]; d2p[3] = s2p[3];
  }
  if (t < 128) {
    const int m = t;
    const int n1 = rbase + (m >> 4);
    const int idx = knn[(((size_t)(b * 4096 + n1)) << 4) + (m & 15)];
    const float* X1 = xyz1 + b * 12288;
    const float* X2 = xyz2 + b * 12288;
    float dx = X2[idx] - X1[n1];
    float dy = X2[4096 + idx] - X1[4096 + n1];
    float dz = X2[8192 + idx] - X1[8192 + n1];
    u32 u0 = (u32)f2bf(dx) | ((u32)f2bf(dy) << 16);
    u32 u1 = (u32)f2bf(dz);
    uint4 pk = make_uint4(u0, u1, 0u, 0u);
    *(uint4*)(F + m * 168 + 128) = pk;
    float d = sqrtf(dx * dx + dy * dy + dz * dz);
    winv[m] = 1.0f / fmaxf(d, 1e-10f);
  } else {
    const int m = t - 128;
    uint4 zz = make_uint4(0u, 0u, 0u, 0u);
    uint4* zp = (uint4*)(F + m * 168 + 136);
    zp[0] = zz; zp[1] = zz; zp[2] = zz; zp[3] = zz;
  }
  __syncthreads();  // barrier 1: F + winv visible

  if (t < 128) {
    const int r = t >> 4;
    float s = 0.f;
#pragma unroll
    for (int k = 0; k < 16; k++) s += winv[(r << 4) + k];
    wnorm[t] = winv[t] / s;
  }

  const int lane = t & 63;
  const int wid = t >> 6;
  const int l15 = lane & 15;
  const int quad = lane >> 4;
  const int koff = quad << 3;
  const int nbase = wid << 5;

  // ---- GEMM1 -------------------------------------------------------------
  f32x4 acc[8][2];
  const f32x4 z4 = {0.f, 0.f, 0.f, 0.f};
#pragma unroll
  for (int i = 0; i < 8; i++)
#pragma unroll
    for (int j = 0; j < 2; j++) acc[i][j] = z4;

#pragma unroll
  for (int s = 0; s < 5; s++) {
    bf16x8 bf0 = ld16(W1b + (nbase + l15) * 160 + s * 32 + koff);
    bf16x8 bf1 = ld16(W1b + (nbase + 16 + l15) * 160 + s * 32 + koff);
#pragma unroll
    for (int mt = 0; mt < 8; mt++) {
      bf16x8 a = ld16(F + (mt * 16 + l15) * 168 + s * 32 + koff);
      acc[mt][0] = MFMA16(a, bf0, acc[mt][0]);
      acc[mt][1] = MFMA16(a, bf1, acc[mt][1]);
    }
  }
  __syncthreads();  // barrier 2: GEMM1 reads done before H1 overwrite

  {
    const float bv0 = b1[nbase + l15];
    const float bv1 = b1[nbase + 16 + l15];
#pragma unroll
    for (int mt = 0; mt < 8; mt++) {
      u16* hrow = F + (mt * 16 + quad * 4) * 168;
#pragma unroll
      for (int r = 0; r < 4; r++) {
        float zv0 = acc[mt][0][r] + bv0;
        zv0 = (zv0 >= 0.f) ? zv0 : 0.1f * zv0;
        hrow[r * 168 + nbase + l15] = f2bf(zv0);
        float zv1 = acc[mt][1][r] + bv1;
        zv1 = (zv1 >= 0.f) ? zv1 : 0.1f * zv1;
        hrow[r * 168 + nbase + 16 + l15] = f2bf(zv1);
      }
    }
  }
  __syncthreads();  // barrier 3: H1 visible

  // ---- GEMM2 -------------------------------------------------------------
  f32x4 acc2[8][2];
#pragma unroll
  for (int i = 0; i < 8; i++)
#pragma unroll
    for (int j = 0; j < 2; j++) acc2[i][j] = z4;

#pragma unroll
  for (int s = 0; s < 4; s++) {
    bf16x8 bf0 = ld16(W2b + (nbase + l15) * 128 + s * 32 + koff);
    bf16x8 bf1 = ld16(W2b + (nbase + 16 + l15) * 128 + s * 32 + koff);
#pragma unroll
    for (int mt = 0; mt < 8; mt++) {
      bf16x8 a = ld16(F + (mt * 16 + l15) * 168 + s * 32 + koff);
      acc2[mt][0] = MFMA16(a, bf0, acc2[mt][0]);
      acc2[mt][1] = MFMA16(a, bf1, acc2[mt][1]);
    }
  }

  {
    const float bv0 = b2[nbase + l15];
    const float bv1 = b2[nbase + 16 + l15];
#pragma unroll
    for (int mt = 0; mt < 8; mt++) {
      const f32x4 w4 = *(const f32x4*)&wnorm[(mt << 4) + (quad << 2)];
      float p0 = 0.f, p1 = 0.f;
#pragma unroll
      for (int r = 0; r < 4; r++) {
        float zv0 = acc2[mt][0][r] + bv0;
        zv0 = (zv0 >= 0.f) ? zv0 : 0.1f * zv0;
        p0 += zv0 * w4[r];
        float zv1 = acc2[mt][1][r] + bv1;
        zv1 = (zv1 >= 0.f) ? zv1 : 0.1f * zv1;
        p1 += zv1 * w4[r];
      }
      p0 += __shfl_xor(p0, 16); p0 += __shfl_xor(p0, 32);
      p1 += __shfl_xor(p1, 16); p1 += __shfl_xor(p1, 32);
      if (quad == 0) {
        outbuf[(nbase + l15) * 12 + mt] = p0;
        outbuf[(nbase + 16 + l15) * 12 + mt] = p1;
      }
    }
  }
  __syncthreads();  // barrier 4: outbuf visible
  {
    const int ch = t >> 1, half = t & 1;
    f32x4 v = *(const f32x4*)&outbuf[ch * 12 + (half << 2)];
    float* op = out + (((size_t)(b * 128 + ch)) << 12) + rbase + (half << 2);
    *(f32x4*)op = v;
  }
}

// ---------------------------------------------------------------------------
extern "C" void kernel_launch(void* const* d_in, const int* in_sizes, int n_in,
                              void* d_out, int out_size, void* d_ws, size_t ws_size,
                              hipStream_t stream) {
  const float* xyz1 = (const float*)d_in[0];
  const float* xyz2 = (const float*)d_in[1];
  const float* points1 = (const float*)d_in[2];
  const float* points2 = (const float*)d_in[3];
  const float* W1 = (const float*)d_in[4];
  const float* b1 = (const float*)d_in[5];
  const float* W2 = (const float*)d_in[6];
  const float* b2 = (const float*)d_in[7];
  float* out = (float*)d_out;

  char* ws = (char*)d_ws;
  int* knn = (int*)ws;                        // 1,048,576 B
  u16* p1t = (u16*)(ws + 1048576);            // 2,097,152 B
  u16* p2t = (u16*)(ws + 3145728);            // 2,097,152 B
  u16* W1b = (u16*)(ws + 5242880);            // 40,960 B
  u16* W2b = (u16*)(ws + 5283840);            // 32,768 B

  hipLaunchKernelGGL(knn_prep, dim3(512), dim3(512), 0, stream,
                     xyz1, xyz2, points1, points2, W1, W2, p1t, p2t, W1b, W2b, knn);
  hipLaunchKernelGGL(mlp_kernel, dim3(2048), dim3(256), 0, stream,
                     xyz1, xyz2, p1t, p2t, knn, W1b, b1, W2b, b2, out);
}